// Round 9
// baseline (95.070 us; speedup 1.0000x reference)
//
#include <hip/hip_runtime.h>
#include <hip/hip_bf16.h>
#include <hip/hip_fp16.h>

#define DIM 512
#define NUM_HEADS 16
#define HEAD_DIM 32
#define WHALF 128
#define MEMN 16
#define SEQ 2048
#define BATCH 2
#define T_TOT (SEQ + MEMN)                 // 2064
#define MROWS (BATCH * T_TOT)              // 4128
#define OROWS (BATCH * SEQ)                // 4096
#define QT 64                              // queries per attn block
#define MAXU 336                           // union-window size (21 chunks of 16)
#define KSTR 40                            // sK row stride (halves)
#define VSTR 344                           // sVt row stride (halves)

typedef _Float16 f16x8 __attribute__((ext_vector_type(8)));
typedef _Float16 f16x4 __attribute__((ext_vector_type(4)));
typedef __fp16   f16raw2 __attribute__((ext_vector_type(2)));   // cvt_pkrtz return
typedef float    f32x4 __attribute__((ext_vector_type(4)));

// ---------------------------------------------------------------------------
// Prep: Wt[n][k] = (fp16) W[k][n]  for the 4 weight matrices
// ---------------------------------------------------------------------------
__global__ __launch_bounds__(256) void cvt_wt(
    const float* __restrict__ Wq, const float* __restrict__ Wk,
    const float* __restrict__ Wv, const float* __restrict__ Wo,
    ushort* __restrict__ Wtq, ushort* __restrict__ Wtk,
    ushort* __restrict__ Wtv, ushort* __restrict__ Wto)
{
    const int w = blockIdx.z;
    const float* W  = w == 0 ? Wq  : (w == 1 ? Wk  : (w == 2 ? Wv  : Wo));
    ushort*     Wt  = w == 0 ? Wtq : (w == 1 ? Wtk : (w == 2 ? Wtv : Wto));

    __shared__ float sT[64][65];
    const int n0 = blockIdx.x * 64;
    const int k0 = blockIdx.y * 64;

    for (int e = threadIdx.x; e < 1024; e += 256) {
        const int r  = e >> 4;
        const int c4 = e & 15;
        const float4 f = *(const float4*)(W + (size_t)(k0 + r) * DIM + n0 + c4 * 4);
        sT[r][c4 * 4 + 0] = f.x;
        sT[r][c4 * 4 + 1] = f.y;
        sT[r][c4 * 4 + 2] = f.z;
        sT[r][c4 * 4 + 3] = f.w;
    }
    __syncthreads();
    for (int u = threadIdx.x; u < 512; u += 256) {
        const int n  = u >> 3;
        const int kg = u & 7;
        union { ushort us[8]; uint4 u4; } o;
        #pragma unroll
        for (int j = 0; j < 8; ++j) {
            _Float16 h = (_Float16)sT[kg * 8 + j][n];
            o.us[j] = *(ushort*)&h;
        }
        *(uint4*)(Wt + (size_t)(n0 + n) * DIM + k0 + kg * 8) = o.u4;
    }
}

// ---------------------------------------------------------------------------
// fp16 MFMA GEMM: C[M][512] = A[M][512] @ Wt^T + bias   (Wt is [512 n][512 k])
// A32: A is fp32 with mem-row mapping (fused cvt); else fp16 flat rows.
// ---------------------------------------------------------------------------
template<bool A32, bool OUT_HALF>
__device__ __forceinline__ void gemm_body(
    const void* __restrict__ Av, const float* __restrict__ memp,
    const ushort* __restrict__ Bt,
    const float* __restrict__ bias, void* __restrict__ C, int M)
{
    __shared__ _Float16 sA[128][72];
    __shared__ _Float16 sB[128][72];

    const int tid  = threadIdx.x;
    const int row0 = blockIdx.x * 128;
    const int col0 = blockIdx.y * 128;
    const int wave = tid >> 6, lane = tid & 63;
    const int wr = wave >> 1, wc = wave & 1;
    const int fr = lane & 15, fq = lane >> 4;

    f32x4 acc[4][4];
    #pragma unroll
    for (int n = 0; n < 4; ++n) {
        const float bb = bias[col0 + wc * 64 + n * 16 + fr];
        #pragma unroll
        for (int m = 0; m < 4; ++m) acc[m][n] = (f32x4){bb, bb, bb, bb};
    }

    for (int k0 = 0; k0 < 512; k0 += 64) {
        __syncthreads();
        #pragma unroll
        for (int it = 0; it < 8; ++it) {
            const int u  = tid + it * 256;
            const int r  = (u >> 3) & 127;
            const int cc = u & 7;
            if (u < 1024) {
                int gr = row0 + r; if (gr >= M) gr = M - 1;
                if (A32) {
                    const int bb = gr >= T_TOT ? 1 : 0;
                    const int t  = gr - bb * T_TOT;
                    const float* src = (t < MEMN)
                        ? (memp + (size_t)t * DIM + k0 + cc * 8)
                        : ((const float*)Av + ((size_t)bb * SEQ + (t - MEMN)) * DIM
                           + k0 + cc * 8);
                    const float4 x0 = ((const float4*)src)[0];
                    const float4 x1 = ((const float4*)src)[1];
                    union { _Float16 hh[8]; uint4 u4; } o;
                    o.hh[0] = (_Float16)x0.x; o.hh[1] = (_Float16)x0.y;
                    o.hh[2] = (_Float16)x0.z; o.hh[3] = (_Float16)x0.w;
                    o.hh[4] = (_Float16)x1.x; o.hh[5] = (_Float16)x1.y;
                    o.hh[6] = (_Float16)x1.z; o.hh[7] = (_Float16)x1.w;
                    *(uint4*)&sA[r][cc * 8] = o.u4;
                } else {
                    *(uint4*)&sA[r][cc * 8] =
                        *(const uint4*)((const ushort*)Av + (size_t)gr * 512
                                        + k0 + cc * 8);
                }
            } else {
                *(uint4*)&sB[r][cc * 8] =
                    *(const uint4*)(Bt + (size_t)(col0 + r) * 512 + k0 + cc * 8);
            }
        }
        __syncthreads();
        #pragma unroll
        for (int kk = 0; kk < 2; ++kk) {
            f16x8 a[4], b[4];
            #pragma unroll
            for (int m = 0; m < 4; ++m)
                a[m] = *(const f16x8*)&sA[wr * 64 + m * 16 + fr][kk * 32 + fq * 8];
            #pragma unroll
            for (int n = 0; n < 4; ++n)
                b[n] = *(const f16x8*)&sB[wc * 64 + n * 16 + fr][kk * 32 + fq * 8];
            #pragma unroll
            for (int m = 0; m < 4; ++m)
                #pragma unroll
                for (int n = 0; n < 4; ++n)
                    acc[m][n] = __builtin_amdgcn_mfma_f32_16x16x32_f16(
                        a[m], b[n], acc[m][n], 0, 0, 0);
        }
    }

    #pragma unroll
    for (int m = 0; m < 4; ++m)
        #pragma unroll
        for (int n = 0; n < 4; ++n)
            #pragma unroll
            for (int j = 0; j < 4; ++j) {
                const int row = row0 + wr * 64 + m * 16 + fq * 4 + j;
                const int col = col0 + wc * 64 + n * 16 + fr;
                if (row < M) {
                    if (OUT_HALF) {
                        _Float16 h = (_Float16)acc[m][n][j];
                        ((ushort*)C)[(size_t)row * 512 + col] = *(ushort*)&h;
                    } else {
                        ((float*)C)[(size_t)row * 512 + col] = acc[m][n][j];
                    }
                }
            }
}

__global__ __launch_bounds__(256) void gemm_qkv(
    const float* __restrict__ q, const float* __restrict__ k,
    const float* __restrict__ v, const float* __restrict__ memp,
    const ushort* __restrict__ Wtq, const ushort* __restrict__ Wtk,
    const ushort* __restrict__ Wtv,
    const float* __restrict__ bq, const float* __restrict__ bk,
    const float* __restrict__ bv,
    ushort* __restrict__ Qc, ushort* __restrict__ Kc, ushort* __restrict__ Vc)
{
    const int w = blockIdx.z;
    const float*  A  = w == 0 ? q   : (w == 1 ? k   : v);
    const ushort* Bt = w == 0 ? Wtq : (w == 1 ? Wtk : Wtv);
    const float*  bi = w == 0 ? bq  : (w == 1 ? bk  : bv);
    ushort*       Cc = w == 0 ? Qc  : (w == 1 ? Kc  : Vc);
    gemm_body<true, true>(A, memp, Bt, bi, Cc, MROWS);
}

__global__ __launch_bounds__(256) void gemm_out(
    const ushort* __restrict__ A, const ushort* __restrict__ Bt,
    const float* __restrict__ bias, float* __restrict__ C)
{
    gemm_body<false, false>(A, nullptr, Bt, bias, C, OROWS);
}

// ---------------------------------------------------------------------------
// MFMA flash attention, 16-key chunks, zero cross-lane P movement.
// Swapped QK^T (A=K, B=Q, 16x16x32): lane(fr,fq) gets S[key ub+fq4+j][q fr]
// == the exact B-fragment of mfma_f32_16x16x16f16 for PV (k=fq4+j, col=fr).
// PV: O^T[d][q] via A=V^T (sVt[d][key]). Defer-max online softmax (T13).
// ---------------------------------------------------------------------------
__global__ __launch_bounds__(256) void attn_mfma(
    const ushort* __restrict__ Q, const ushort* __restrict__ K,
    const ushort* __restrict__ V, ushort* __restrict__ ctx)
{
    const int tid  = threadIdx.x;
    const int tile = blockIdx.x, h = blockIdx.y, b = blockIdx.z;
    const int wave = tid >> 6, lane = tid & 63;
    const int fr = lane & 15, fq = lane >> 4;
    const int fq8 = fq * 8, fq4 = fq * 4;

    const int i0  = MEMN + tile * QT;
    const int klo = max(MEMN, i0 - WHALF);
    const int khi = min(T_TOT - 1, i0 + QT - 1 + WHALF);
    const int total  = MEMN + khi - klo + 1;           // <= 336
    const int ustage = (total + 15) & ~15;             // staged rows (16-mult)

    __shared__ ushort sK[MAXU][KSTR];                  // 26.3 KiB
    __shared__ ushort sVt[HEAD_DIM][VSTR];             // 21.5 KiB

    const size_t hbase = (size_t)b * T_TOT * DIM + (size_t)h * HEAD_DIM;

    // ---- stage K rows (zero-fill chunk tails) ----
    for (int idx = tid; idx < ustage * 4; idx += 256) {
        const int u = idx >> 2, c = idx & 3;
        uint4 val = {0, 0, 0, 0};
        if (u < total) {
            const int g = (u < MEMN) ? u : klo + u - MEMN;
            val = *(const uint4*)(K + hbase + (size_t)g * DIM + c * 8);
        }
        *(uint4*)&sK[u][c * 8] = val;
    }
    // ---- stage V transposed: u32 = (key u2, u2+1) pair per d ----
    for (int idx = tid; idx < (ustage / 2) * 4; idx += 256) {
        const int u2 = (idx >> 2) * 2, c = idx & 3;
        union { uint4 q4; ushort us[8]; } r0, r1;
        r0.q4 = (uint4){0, 0, 0, 0};
        r1.q4 = (uint4){0, 0, 0, 0};
        if (u2 < total) {
            const int g0 = (u2 < MEMN) ? u2 : klo + u2 - MEMN;
            r0.q4 = *(const uint4*)(V + hbase + (size_t)g0 * DIM + c * 8);
        }
        if (u2 + 1 < total) {
            const int g1 = (u2 + 1 < MEMN) ? u2 + 1 : klo + u2 + 1 - MEMN;
            r1.q4 = *(const uint4*)(V + hbase + (size_t)g1 * DIM + c * 8);
        }
        #pragma unroll
        for (int ii = 0; ii < 8; ++ii) {               // rotate to spread banks
            const int i = (ii + (u2 >> 1)) & 7;
            const uint w = (uint)r0.us[i] | ((uint)r1.us[i] << 16);
            *(uint*)&sVt[c * 8 + i][u2] = w;
        }
    }

    // ---- Q fragment (B operand): lane holds Q[q=fr][d=fq*8..+7] ----
    const int iq = i0 + wave * 16 + fr;                // this lane's query
    const f16x8 qf = *(const f16x8*)(Q + (size_t)(b * T_TOT + iq) * DIM
                                     + h * HEAD_DIM + fq8);

    // per-query valid union-index range [ulo, uhi] (u<16 = mem, unmasked)
    const int ulo  = max(iq - WHALF - klo, 0) + MEMN;
    const int uhi  = min(iq + WHALF, khi) - klo + MEMN;
    const int span = uhi - ulo;
    const int iw0  = i0 + wave * 16;
    const int ulo_minw = max(iw0 - WHALF - klo, 0) + MEMN;
    const int ulo_maxw = max(iw0 + 15 - WHALF - klo, 0) + MEMN;
    const int uhi_minw = min(iw0 + WHALF, khi) - klo + MEMN;
    const int uhi_maxw = min(iw0 + 15 + WHALF, khi) - klo + MEMN;

    __syncthreads();

    const float scale  = 0.17677669529663687f;         // 1/sqrt(32)
    const float NEGINF = -__builtin_huge_valf();
    float mns = 0.0f;                                  // running max * scale
    float l   = 0.f;
    f32x4 oc0 = {0, 0, 0, 0}, oc1 = {0, 0, 0, 0};      // O^T rows fq4+j (+16)

    const int nchunks = (total + 15) >> 4;

    for (int ch = 0; ch < nchunks; ++ch) {
        const int ub = ch * 16;
        if (ub >= MEMN && (ub > uhi_maxw || ub + 15 < ulo_minw)) continue;
        const bool needMask =
            !((ub == 0) || (ub >= ulo_maxw && ub + 15 <= uhi_minw));

        // ---- QK^T for 16 keys ----
        const f16x8 kf = *(const f16x8*)&sK[ub + fr][fq8];
        f32x4 s4 = {0, 0, 0, 0};
        s4 = __builtin_amdgcn_mfma_f32_16x16x32_f16(kf, qf, s4, 0, 0, 0);
        if (needMask) {
            #pragma unroll
            for (int j = 0; j < 4; ++j) {
                const uint uu = (uint)(ub + fq4 + j - ulo);
                s4[j] = (uu <= (uint)span) ? s4[j] : NEGINF;
            }
        }

        // ---- defer-max online softmax (group = 4 fq-lanes of query fr) ----
        float mx = fmaxf(fmaxf(s4[0], s4[1]), fmaxf(s4[2], s4[3]));
        mx = fmaxf(mx, __shfl_xor(mx, 16));
        mx = fmaxf(mx, __shfl_xor(mx, 32));
        const float mxs = mx * scale;
        if (!__all(mxs <= mns)) {
            const float mn2   = fmaxf(mns, mxs);
            const float alpha = __expf(mns - mn2);
            l *= alpha;
            #pragma unroll
            for (int j = 0; j < 4; ++j) { oc0[j] *= alpha; oc1[j] *= alpha; }
            mns = mn2;
        }
        const float p0 = __expf(fmaf(s4[0], scale, -mns));
        const float p1 = __expf(fmaf(s4[1], scale, -mns));
        const float p2 = __expf(fmaf(s4[2], scale, -mns));
        const float p3 = __expf(fmaf(s4[3], scale, -mns));
        l += (p0 + p1) + (p2 + p3);

        // ---- P already in PV B-frag layout: pack to fp16, no shuffles ----
        union { f16raw2 h2; uint u; } c0, c1;
        c0.h2 = __builtin_amdgcn_cvt_pkrtz(p0, p1);
        c1.h2 = __builtin_amdgcn_cvt_pkrtz(p2, p3);
        union { uint u[2]; f16x4 h; } P;
        P.u[0] = c0.u;
        P.u[1] = c1.u;

        // ---- PV: O^T += V^T @ P^T (two 16x16x16, d rows 0-15 / 16-31) ----
        const f16x4 va0 = *(const f16x4*)&sVt[fr][ub + fq4];
        const f16x4 va1 = *(const f16x4*)&sVt[fr + 16][ub + fq4];
        oc0 = __builtin_amdgcn_mfma_f32_16x16x16f16(va0, P.h, oc0, 0, 0, 0);
        oc1 = __builtin_amdgcn_mfma_f32_16x16x16f16(va1, P.h, oc1, 0, 0, 0);
    }

    // ---- finalize: l reduce across fq group, divide, store fp16 ----
    l += __shfl_xor(l, 16);
    l += __shfl_xor(l, 32);
    const float inv = 1.0f / l;
    union { f16raw2 h2; uint u; } w00, w01, w10, w11;
    w00.h2 = __builtin_amdgcn_cvt_pkrtz(oc0[0] * inv, oc0[1] * inv);
    w01.h2 = __builtin_amdgcn_cvt_pkrtz(oc0[2] * inv, oc0[3] * inv);
    w10.h2 = __builtin_amdgcn_cvt_pkrtz(oc1[0] * inv, oc1[1] * inv);
    w11.h2 = __builtin_amdgcn_cvt_pkrtz(oc1[2] * inv, oc1[3] * inv);
    ushort* cp = ctx + ((size_t)b * SEQ + (iq - MEMN)) * DIM
               + h * HEAD_DIM + fq4;
    *(uint2*)cp        = (uint2){w00.u, w01.u};        // d = fq*4 .. +3
    *(uint2*)(cp + 16) = (uint2){w10.u, w11.u};        // d = 16+fq*4 .. +3
}

// ---------------------------------------------------------------------------
extern "C" void kernel_launch(void* const* d_in, const int* in_sizes, int n_in,
                              void* d_out, int out_size, void* d_ws, size_t ws_size,
                              hipStream_t stream) {
    const float* q    = (const float*)d_in[0];
    const float* k    = (const float*)d_in[1];
    const float* v    = (const float*)d_in[2];
    const float* memp = (const float*)d_in[3];
    const float* Wq   = (const float*)d_in[4];
    const float* bq   = (const float*)d_in[5];
    const float* Wk   = (const float*)d_in[6];
    const float* bk   = (const float*)d_in[7];
    const float* Wv   = (const float*)d_in[8];
    const float* bv   = (const float*)d_in[9];
    const float* Wo   = (const float*)d_in[10];
    const float* bo   = (const float*)d_in[11];
    float* out = (float*)d_out;

    const size_t NX = (size_t)MROWS * DIM;
    const size_t NW = (size_t)DIM * DIM;
    const size_t NC = (size_t)OROWS * DIM;

    ushort* p   = (ushort*)d_ws;
    ushort* Qc  = p;            p += NX;
    ushort* Kc  = p;            p += NX;
    ushort* Vc  = p;            p += NX;
    ushort* Wtq = p;            p += NW;
    ushort* Wtk = p;            p += NW;
    ushort* Wtv = p;            p += NW;
    ushort* Wto = p;            p += NW;
    ushort* Cc  = p;            p += NC;               // ~19 MB total

    dim3 gw(8, 8, 4);
    cvt_wt<<<gw, 256, 0, stream>>>(Wq, Wk, Wv, Wo, Wtq, Wtk, Wtv, Wto);

    dim3 g1((MROWS + 127) / 128, 4, 3);
    gemm_qkv<<<g1, 256, 0, stream>>>(q, k, v, memp, Wtq, Wtk, Wtv,
                                     bq, bk, bv, Qc, Kc, Vc);

    dim3 g2(SEQ / QT, NUM_HEADS, BATCH);
    attn_mfma<<<g2, 256, 0, stream>>>(Qc, Kc, Vc, Cc);

    dim3 g3(OROWS / 128, 4, 1);
    gemm_out<<<g3, 256, 0, stream>>>(Cc, Wto, bo, out);
}

// Round 11
// 84.171 us; speedup vs baseline: 1.1295x; 1.1295x over previous
//
#include <hip/hip_runtime.h>
#include <hip/hip_bf16.h>
#include <hip/hip_fp16.h>

#define DIM 512
#define NUM_HEADS 16
#define HEAD_DIM 32
#define WHALF 128
#define MEMN 16
#define SEQ 2048
#define BATCH 2
#define T_TOT (SEQ + MEMN)                 // 2064
#define MROWS (BATCH * T_TOT)              // 4128
#define OROWS (BATCH * SEQ)                // 4096
#define QT 128                             // queries per attn block (8 waves)
#define MAXU 416                           // pad32 of max union window (401)
#define KSTR 40                            // sK row stride (halves), 80B
#define VSTR 424                           // sVt row stride (halves), 848B

typedef _Float16 f16x8 __attribute__((ext_vector_type(8)));
typedef __fp16   f16raw2 __attribute__((ext_vector_type(2)));   // cvt_pkrtz return
typedef float    f32x4 __attribute__((ext_vector_type(4)));

// ---------------------------------------------------------------------------
// Prep 1: build fp16 X matrices [MROWS x 512] for q,k,v (mem rows prepended)
// ---------------------------------------------------------------------------
__global__ __launch_bounds__(256) void cvt_x(
    const float* __restrict__ q, const float* __restrict__ k,
    const float* __restrict__ v, const float* __restrict__ memp,
    ushort* __restrict__ Xq, ushort* __restrict__ Xk, ushort* __restrict__ Xv)
{
    const int which = blockIdx.z;
    const float* X = which == 0 ? q : (which == 1 ? k : v);
    ushort*     Xc = which == 0 ? Xq : (which == 1 ? Xk : Xv);

    const int gid  = blockIdx.x * 256 + threadIdx.x;
    const int base = gid * 8;
    if (base >= MROWS * DIM) return;
    const int row = base >> 9;
    const int c   = base & 511;
    const int b   = row / T_TOT;
    const int t   = row - b * T_TOT;
    const float* src = (t < MEMN)
        ? (memp + (size_t)t * DIM + c)
        : (X + ((size_t)b * SEQ + (t - MEMN)) * DIM + c);
    const float4 a0 = *(const float4*)src;
    const float4 a1 = *(const float4*)(src + 4);
    union { _Float16 hh[8]; uint4 u4; } o;
    o.hh[0] = (_Float16)a0.x; o.hh[1] = (_Float16)a0.y;
    o.hh[2] = (_Float16)a0.z; o.hh[3] = (_Float16)a0.w;
    o.hh[4] = (_Float16)a1.x; o.hh[5] = (_Float16)a1.y;
    o.hh[6] = (_Float16)a1.z; o.hh[7] = (_Float16)a1.w;
    *(uint4*)(Xc + (size_t)row * DIM + c) = o.u4;
}

// ---------------------------------------------------------------------------
// Prep 2: Wt[n][k] = (fp16) W[k][n]  for the 4 weight matrices
// ---------------------------------------------------------------------------
__global__ __launch_bounds__(256) void cvt_wt(
    const float* __restrict__ Wq, const float* __restrict__ Wk,
    const float* __restrict__ Wv, const float* __restrict__ Wo,
    ushort* __restrict__ Wtq, ushort* __restrict__ Wtk,
    ushort* __restrict__ Wtv, ushort* __restrict__ Wto)
{
    const int w = blockIdx.z;
    const float* W  = w == 0 ? Wq  : (w == 1 ? Wk  : (w == 2 ? Wv  : Wo));
    ushort*     Wt  = w == 0 ? Wtq : (w == 1 ? Wtk : (w == 2 ? Wtv : Wto));

    __shared__ float sT[64][65];
    const int n0 = blockIdx.x * 64;
    const int k0 = blockIdx.y * 64;

    for (int e = threadIdx.x; e < 1024; e += 256) {
        const int r  = e >> 4;
        const int c4 = e & 15;
        const float4 f = *(const float4*)(W + (size_t)(k0 + r) * DIM + n0 + c4 * 4);
        sT[r][c4 * 4 + 0] = f.x;
        sT[r][c4 * 4 + 1] = f.y;
        sT[r][c4 * 4 + 2] = f.z;
        sT[r][c4 * 4 + 3] = f.w;
    }
    __syncthreads();
    for (int u = threadIdx.x; u < 512; u += 256) {
        const int n  = u >> 3;
        const int kg = u & 7;
        union { ushort us[8]; uint4 u4; } o;
        #pragma unroll
        for (int j = 0; j < 8; ++j) {
            _Float16 h = (_Float16)sT[kg * 8 + j][n];
            o.us[j] = *(ushort*)&h;
        }
        *(uint4*)(Wt + (size_t)(n0 + n) * DIM + k0 + kg * 8) = o.u4;
    }
}

// ---------------------------------------------------------------------------
// fp16 MFMA GEMM (round-8 proven): C[M][512] = A[M][512] @ Wt^T + bias
// ---------------------------------------------------------------------------
template<bool OUT_HALF>
__device__ __forceinline__ void gemm_body(
    const ushort* __restrict__ A, const ushort* __restrict__ Bt,
    const float* __restrict__ bias, void* __restrict__ C, int M)
{
    __shared__ _Float16 sA[128][72];
    __shared__ _Float16 sB[128][72];

    const int tid  = threadIdx.x;
    const int row0 = blockIdx.x * 128;
    const int col0 = blockIdx.y * 128;
    const int wave = tid >> 6, lane = tid & 63;
    const int wr = wave >> 1, wc = wave & 1;
    const int fr = lane & 15, fq = lane >> 4;

    f32x4 acc[4][4];
    #pragma unroll
    for (int n = 0; n < 4; ++n) {
        const float bb = bias[col0 + wc * 64 + n * 16 + fr];
        #pragma unroll
        for (int m = 0; m < 4; ++m) acc[m][n] = (f32x4){bb, bb, bb, bb};
    }

    for (int k0 = 0; k0 < 512; k0 += 64) {
        __syncthreads();
        #pragma unroll
        for (int it = 0; it < 8; ++it) {
            const int u  = tid + it * 256;
            const int r  = (u >> 3) & 127;
            const int cc = u & 7;
            if (u < 1024) {
                int gr = row0 + r; if (gr >= M) gr = M - 1;
                *(uint4*)&sA[r][cc * 8] =
                    *(const uint4*)(A + (size_t)gr * 512 + k0 + cc * 8);
            } else {
                *(uint4*)&sB[r][cc * 8] =
                    *(const uint4*)(Bt + (size_t)(col0 + r) * 512 + k0 + cc * 8);
            }
        }
        __syncthreads();
        #pragma unroll
        for (int kk = 0; kk < 2; ++kk) {
            f16x8 a[4], b[4];
            #pragma unroll
            for (int m = 0; m < 4; ++m)
                a[m] = *(const f16x8*)&sA[wr * 64 + m * 16 + fr][kk * 32 + fq * 8];
            #pragma unroll
            for (int n = 0; n < 4; ++n)
                b[n] = *(const f16x8*)&sB[wc * 64 + n * 16 + fr][kk * 32 + fq * 8];
            #pragma unroll
            for (int m = 0; m < 4; ++m)
                #pragma unroll
                for (int n = 0; n < 4; ++n)
                    acc[m][n] = __builtin_amdgcn_mfma_f32_16x16x32_f16(
                        a[m], b[n], acc[m][n], 0, 0, 0);
        }
    }

    #pragma unroll
    for (int m = 0; m < 4; ++m)
        #pragma unroll
        for (int n = 0; n < 4; ++n)
            #pragma unroll
            for (int j = 0; j < 4; ++j) {
                const int row = row0 + wr * 64 + m * 16 + fq * 4 + j;
                const int col = col0 + wc * 64 + n * 16 + fr;
                if (row < M) {
                    if (OUT_HALF) {
                        _Float16 h = (_Float16)acc[m][n][j];
                        ((ushort*)C)[(size_t)row * 512 + col] = *(ushort*)&h;
                    } else {
                        ((float*)C)[(size_t)row * 512 + col] = acc[m][n][j];
                    }
                }
            }
}

__global__ __launch_bounds__(256) void gemm_qkv(
    const ushort* __restrict__ Xq, const ushort* __restrict__ Xk,
    const ushort* __restrict__ Xv,
    const ushort* __restrict__ Wtq, const ushort* __restrict__ Wtk,
    const ushort* __restrict__ Wtv,
    const float* __restrict__ bq, const float* __restrict__ bk,
    const float* __restrict__ bv,
    ushort* __restrict__ Qc, ushort* __restrict__ Kc, ushort* __restrict__ Vc)
{
    const int w = blockIdx.z;
    const ushort* A  = w == 0 ? Xq  : (w == 1 ? Xk  : Xv);
    const ushort* Bt = w == 0 ? Wtq : (w == 1 ? Wtk : Wtv);
    const float*  bi = w == 0 ? bq  : (w == 1 ? bk  : bv);
    ushort*       Cc = w == 0 ? Qc  : (w == 1 ? Kc  : Vc);
    gemm_body<true>(A, Bt, bi, Cc, MROWS);
}

__global__ __launch_bounds__(256) void gemm_out(
    const ushort* __restrict__ A, const ushort* __restrict__ Bt,
    const float* __restrict__ bias, float* __restrict__ C)
{
    gemm_body<false>(A, Bt, bias, C, OROWS);
}

// ---------------------------------------------------------------------------
// MFMA flash attention: 8 waves x 16 queries (QT=128), 32-key groups.
// QK^T swapped (A=K, B=Q): lane(fr,fq) gets S[key 4fq+j][q fr] per 16-chunk.
// PV K=32 with PERMUTED sVt columns (k'=8fq+e ↦ key e<4 ? 4fq+e : 16+4fq+e-4)
// so the two score fragments ARE the PV B-fragment — zero cross-lane traffic.
// Staging writes rotated to kill the 4-way c-lane bank aliasing (20*8c≡0 mod32).
// ---------------------------------------------------------------------------
__global__ __launch_bounds__(512, 4) void attn_mfma(
    const ushort* __restrict__ Q, const ushort* __restrict__ K,
    const ushort* __restrict__ V, ushort* __restrict__ ctx)
{
    const int tid  = threadIdx.x;
    const int tile = blockIdx.x, h = blockIdx.y, b = blockIdx.z;
    const int wave = tid >> 6, lane = tid & 63;
    const int fr = lane & 15, fq = lane >> 4;
    const int fq8 = fq * 8, fq4 = fq * 4;

    const int i0  = MEMN + tile * QT;
    const int klo = max(MEMN, i0 - WHALF);
    const int khi = min(T_TOT - 1, i0 + QT - 1 + WHALF);
    const int total  = MEMN + khi - klo + 1;           // <= 401
    const int ustage = (total + 31) & ~31;             // pad to 32

    __shared__ ushort sK[MAXU][KSTR];                  // 33.3 KiB
    __shared__ ushort sVt[HEAD_DIM][VSTR];             // 27.1 KiB

    const size_t hbase = (size_t)b * T_TOT * DIM + (size_t)h * HEAD_DIM;

    // ---- stage K rows; chunk rotated by (c+u)&3 for bank spread ----
    for (int idx = tid; idx < ustage * 4; idx += 512) {
        const int u = idx >> 2, c = idx & 3;
        const int cc = (c + u) & 3;
        uint4 val = {0, 0, 0, 0};
        if (u < total) {
            const int g = (u < MEMN) ? u : klo + u - MEMN;
            val = *(const uint4*)(K + hbase + (size_t)g * DIM + cc * 8);
        }
        *(uint4*)&sK[u][cc * 8] = val;
    }
    // ---- stage V transposed into PERMUTED key columns ----
    for (int idx = tid; idx < (ustage / 2) * 4; idx += 512) {
        const int pr = idx >> 2;                       // key-pair index
        const int u2 = pr * 2, c = idx & 3;
        union { uint4 q4; ushort us[8]; } r0, r1;
        r0.q4 = (uint4){0, 0, 0, 0};
        r1.q4 = (uint4){0, 0, 0, 0};
        if (u2 < total) {
            const int g0 = (u2 < MEMN) ? u2 : klo + u2 - MEMN;
            r0.q4 = *(const uint4*)(V + hbase + (size_t)g0 * DIM + c * 8);
        }
        if (u2 + 1 < total) {
            const int g1 = (u2 + 1 < MEMN) ? u2 + 1 : klo + u2 + 1 - MEMN;
            r1.q4 = *(const uint4*)(V + hbase + (size_t)g1 * DIM + c * 8);
        }
        // permuted word index within the 32-key group
        const int g  = u2 & 31, gb = u2 & ~31;
        const int w  = (g < 16) ? ((g >> 2) * 4 + ((g >> 1) & 1))
                                : (((g - 16) >> 2) * 4 + 2 + (((g - 16) >> 1) & 1));
        const int col = gb + w * 2;                    // halves index (u32 word)
        #pragma unroll
        for (int ii = 0; ii < 8; ++ii) {               // row rotate: c re-enters bank idx
            const int i = (ii + pr + 2 * c) & 7;
            const uint wv = (uint)r0.us[i] | ((uint)r1.us[i] << 16);
            *(uint*)&sVt[c * 8 + i][col] = wv;
        }
    }

    // ---- Q fragment (B operand): lane holds Q[q=fr][d=fq*8..+7] ----
    const int iq = i0 + wave * 16 + fr;
    const f16x8 qf = *(const f16x8*)(Q + (size_t)(b * T_TOT + iq) * DIM
                                     + h * HEAD_DIM + fq8);

    const int ulo  = max(iq - WHALF - klo, 0) + MEMN;
    const int uhi  = min(iq + WHALF, khi) - klo + MEMN;
    const int span = uhi - ulo;
    const int iw0  = i0 + wave * 16;
    const int ulo_minw = max(iw0 - WHALF - klo, 0) + MEMN;
    const int ulo_maxw = max(iw0 + 15 - WHALF - klo, 0) + MEMN;
    const int uhi_minw = min(iw0 + WHALF, khi) - klo + MEMN;
    const int uhi_maxw = min(iw0 + 15 + WHALF, khi) - klo + MEMN;

    __syncthreads();

    const float scale  = 0.17677669529663687f;         // 1/sqrt(32)
    const float NEGINF = -__builtin_huge_valf();
    float mns = 0.0f;                                  // running max * scale
    float l   = 0.f;
    f32x4 oc0 = {0, 0, 0, 0}, oc1 = {0, 0, 0, 0};      // O^T rows fq4+j (+16)

    const int ng = ustage >> 5;

    for (int gi = 0; gi < ng; ++gi) {
        const int ub = gi * 32;
        if (ub != 0 && (ub > uhi_maxw || ub + 31 < ulo_minw)) continue;
        const int ubB = ub + 16;
        const bool maskA = !((ub == 0) || (ub >= ulo_maxw && ub + 15 <= uhi_minw));
        const bool maskB = !(ubB >= ulo_maxw && ubB + 15 <= uhi_minw);

        // ---- QK^T: two 16-key chunks (K contraction = HEAD_DIM = 32) ----
        const f16x8 kfA = *(const f16x8*)&sK[ub + fr][fq8];
        const f16x8 kfB = *(const f16x8*)&sK[ubB + fr][fq8];
        f32x4 sA = {0, 0, 0, 0}, sB = {0, 0, 0, 0};
        sA = __builtin_amdgcn_mfma_f32_16x16x32_f16(kfA, qf, sA, 0, 0, 0);
        sB = __builtin_amdgcn_mfma_f32_16x16x32_f16(kfB, qf, sB, 0, 0, 0);
        if (maskA) {
            #pragma unroll
            for (int j = 0; j < 4; ++j) {
                const uint uu = (uint)(ub + fq4 + j - ulo);
                sA[j] = (uu <= (uint)span) ? sA[j] : NEGINF;
            }
        }
        if (maskB) {
            #pragma unroll
            for (int j = 0; j < 4; ++j) {
                const uint uu = (uint)(ubB + fq4 + j - ulo);
                sB[j] = (uu <= (uint)span) ? sB[j] : NEGINF;
            }
        }

        // ---- joint 32-key defer-max online softmax ----
        float mx = fmaxf(fmaxf(fmaxf(sA[0], sA[1]), fmaxf(sA[2], sA[3])),
                         fmaxf(fmaxf(sB[0], sB[1]), fmaxf(sB[2], sB[3])));
        mx = fmaxf(mx, __shfl_xor(mx, 16));
        mx = fmaxf(mx, __shfl_xor(mx, 32));
        const float mxs = mx * scale;
        if (!__all(mxs <= mns)) {
            const float mn2   = fmaxf(mns, mxs);
            const float alpha = __expf(mns - mn2);
            l *= alpha;
            #pragma unroll
            for (int j = 0; j < 4; ++j) { oc0[j] *= alpha; oc1[j] *= alpha; }
            mns = mn2;
        }
        const float p0 = __expf(fmaf(sA[0], scale, -mns));
        const float p1 = __expf(fmaf(sA[1], scale, -mns));
        const float p2 = __expf(fmaf(sA[2], scale, -mns));
        const float p3 = __expf(fmaf(sA[3], scale, -mns));
        const float p4 = __expf(fmaf(sB[0], scale, -mns));
        const float p5 = __expf(fmaf(sB[1], scale, -mns));
        const float p6 = __expf(fmaf(sB[2], scale, -mns));
        const float p7 = __expf(fmaf(sB[3], scale, -mns));
        l += ((p0 + p1) + (p2 + p3)) + ((p4 + p5) + (p6 + p7));

        // ---- P is ALREADY the K=32 PV B-fragment (via permuted sVt) ----
        union { f16raw2 h2; uint u; } c0, c1, c2, c3;
        c0.h2 = __builtin_amdgcn_cvt_pkrtz(p0, p1);
        c1.h2 = __builtin_amdgcn_cvt_pkrtz(p2, p3);
        c2.h2 = __builtin_amdgcn_cvt_pkrtz(p4, p5);
        c3.h2 = __builtin_amdgcn_cvt_pkrtz(p6, p7);
        union { uint u[4]; f16x8 h; } P;
        P.u[0] = c0.u; P.u[1] = c1.u; P.u[2] = c2.u; P.u[3] = c3.u;

        // ---- PV: O^T += V^T @ P^T (two 16x16x32, d rows 0-15 / 16-31) ----
        const f16x8 va0 = *(const f16x8*)&sVt[fr][ub + fq8];
        const f16x8 va1 = *(const f16x8*)&sVt[fr + 16][ub + fq8];
        oc0 = __builtin_amdgcn_mfma_f32_16x16x32_f16(va0, P.h, oc0, 0, 0, 0);
        oc1 = __builtin_amdgcn_mfma_f32_16x16x32_f16(va1, P.h, oc1, 0, 0, 0);
    }

    // ---- finalize: l reduce across fq group, divide, store fp16 ----
    l += __shfl_xor(l, 16);
    l += __shfl_xor(l, 32);
    const float inv = 1.0f / l;
    union { f16raw2 h2; uint u; } w00, w01, w10, w11;
    w00.h2 = __builtin_amdgcn_cvt_pkrtz(oc0[0] * inv, oc0[1] * inv);
    w01.h2 = __builtin_amdgcn_cvt_pkrtz(oc0[2] * inv, oc0[3] * inv);
    w10.h2 = __builtin_amdgcn_cvt_pkrtz(oc1[0] * inv, oc1[1] * inv);
    w11.h2 = __builtin_amdgcn_cvt_pkrtz(oc1[2] * inv, oc1[3] * inv);
    ushort* cp = ctx + ((size_t)b * SEQ + (iq - MEMN)) * DIM
               + h * HEAD_DIM + fq4;
    *(uint2*)cp        = (uint2){w00.u, w01.u};        // d = fq*4 .. +3
    *(uint2*)(cp + 16) = (uint2){w10.u, w11.u};        // d = 16+fq*4 .. +3
}

// ---------------------------------------------------------------------------
extern "C" void kernel_launch(void* const* d_in, const int* in_sizes, int n_in,
                              void* d_out, int out_size, void* d_ws, size_t ws_size,
                              hipStream_t stream) {
    const float* q    = (const float*)d_in[0];
    const float* k    = (const float*)d_in[1];
    const float* v    = (const float*)d_in[2];
    const float* memp = (const float*)d_in[3];
    const float* Wq   = (const float*)d_in[4];
    const float* bq   = (const float*)d_in[5];
    const float* Wk   = (const float*)d_in[6];
    const float* bk   = (const float*)d_in[7];
    const float* Wv   = (const float*)d_in[8];
    const float* bv   = (const float*)d_in[9];
    const float* Wo   = (const float*)d_in[10];
    const float* bo   = (const float*)d_in[11];
    float* out = (float*)d_out;

    const size_t NX = (size_t)MROWS * DIM;
    const size_t NW = (size_t)DIM * DIM;
    const size_t NC = (size_t)OROWS * DIM;

    ushort* p   = (ushort*)d_ws;
    ushort* Xq  = p;            p += NX;
    ushort* Xk  = p;            p += NX;
    ushort* Xv  = p;            p += NX;
    ushort* Qc  = p;            p += NX;
    ushort* Kc  = p;            p += NX;
    ushort* Vc  = p;            p += NX;
    ushort* Wtq = p;            p += NW;
    ushort* Wtk = p;            p += NW;
    ushort* Wtv = p;            p += NW;
    ushort* Wto = p;            p += NW;
    ushort* Cc  = p;            p += NC;               // ~31.7 MB total

    dim3 gx((MROWS * DIM / 8 + 255) / 256, 1, 3);
    cvt_x<<<gx, 256, 0, stream>>>(q, k, v, memp, Xq, Xk, Xv);

    dim3 gw(8, 8, 4);
    cvt_wt<<<gw, 256, 0, stream>>>(Wq, Wk, Wv, Wo, Wtq, Wtk, Wtv, Wto);

    dim3 g1((MROWS + 127) / 128, 4, 3);
    gemm_qkv<<<g1, 256, 0, stream>>>(Xq, Xk, Xv, Wtq, Wtk, Wtv,
                                     bq, bk, bv, Qc, Kc, Vc);

    dim3 g2(SEQ / QT, NUM_HEADS, BATCH);
    attn_mfma<<<g2, 512, 0, stream>>>(Qc, Kc, Vc, Cc);

    dim3 g3(OROWS / 128, 4, 1);
    gemm_out<<<g3, 256, 0, stream>>>(Cc, Wto, bo, out);
}

// Round 12
// 80.675 us; speedup vs baseline: 1.1784x; 1.0433x over previous
//
#include <hip/hip_runtime.h>
#include <hip/hip_bf16.h>
#include <hip/hip_fp16.h>

#define DIM 512
#define NUM_HEADS 16
#define HEAD_DIM 32
#define WHALF 128
#define MEMN 16
#define SEQ 2048
#define BATCH 2
#define T_TOT (SEQ + MEMN)                 // 2064
#define MROWS (BATCH * T_TOT)              // 4128
#define OROWS (BATCH * SEQ)                // 4096
#define QT 128                             // queries per attn block (8 waves)
#define MAXU 416                           // pad32 of max union window (401)
#define KSTR 40                            // sK row stride (halves), 80B
#define VSTR 424                           // sVt row stride (halves), 848B

typedef _Float16 f16x8 __attribute__((ext_vector_type(8)));
typedef __fp16   f16raw2 __attribute__((ext_vector_type(2)));   // cvt_pkrtz return
typedef float    f32x4 __attribute__((ext_vector_type(4)));

#define QSCALE 0.17677669529663687f        // 1/sqrt(32), folded into Wq/bq

// ---------------------------------------------------------------------------
// Merged prep: z in [0,3): fp16 X matrices; z in [3,7): Wt[n][k] = W[k][n].
// Wq is pre-scaled by QSCALE so attention needs no score scaling.
// ---------------------------------------------------------------------------
__global__ __launch_bounds__(256) void prep_cvt(
    const float* __restrict__ q, const float* __restrict__ k,
    const float* __restrict__ v, const float* __restrict__ memp,
    const float* __restrict__ Wq, const float* __restrict__ Wk,
    const float* __restrict__ Wv, const float* __restrict__ Wo,
    ushort* __restrict__ Xq, ushort* __restrict__ Xk, ushort* __restrict__ Xv,
    ushort* __restrict__ Wtq, ushort* __restrict__ Wtk,
    ushort* __restrict__ Wtv, ushort* __restrict__ Wto)
{
    const int z = blockIdx.z;
    if (z < 3) {
        const float* X = z == 0 ? q : (z == 1 ? k : v);
        ushort*     Xc = z == 0 ? Xq : (z == 1 ? Xk : Xv);
        const int gid  = blockIdx.x * 256 + threadIdx.x;
        const int base = gid * 8;
        if (base >= MROWS * DIM) return;
        const int row = base >> 9;
        const int c   = base & 511;
        const int b   = row / T_TOT;
        const int t   = row - b * T_TOT;
        const float* src = (t < MEMN)
            ? (memp + (size_t)t * DIM + c)
            : (X + ((size_t)b * SEQ + (t - MEMN)) * DIM + c);
        const float4 a0 = *(const float4*)src;
        const float4 a1 = *(const float4*)(src + 4);
        union { _Float16 hh[8]; uint4 u4; } o;
        o.hh[0] = (_Float16)a0.x; o.hh[1] = (_Float16)a0.y;
        o.hh[2] = (_Float16)a0.z; o.hh[3] = (_Float16)a0.w;
        o.hh[4] = (_Float16)a1.x; o.hh[5] = (_Float16)a1.y;
        o.hh[6] = (_Float16)a1.z; o.hh[7] = (_Float16)a1.w;
        *(uint4*)(Xc + (size_t)row * DIM + c) = o.u4;
        return;
    }
    // weight transpose path
    if (blockIdx.x >= 64) return;
    const int w = z - 3;
    const float* W  = w == 0 ? Wq  : (w == 1 ? Wk  : (w == 2 ? Wv  : Wo));
    ushort*     Wt  = w == 0 ? Wtq : (w == 1 ? Wtk : (w == 2 ? Wtv : Wto));
    const float ws  = (w == 0) ? QSCALE : 1.0f;

    __shared__ float sT[64][65];
    const int n0 = (blockIdx.x & 7) * 64;
    const int k0 = (blockIdx.x >> 3) * 64;

    for (int e = threadIdx.x; e < 1024; e += 256) {
        const int r  = e >> 4;
        const int c4 = e & 15;
        const float4 f = *(const float4*)(W + (size_t)(k0 + r) * DIM + n0 + c4 * 4);
        sT[r][c4 * 4 + 0] = f.x;
        sT[r][c4 * 4 + 1] = f.y;
        sT[r][c4 * 4 + 2] = f.z;
        sT[r][c4 * 4 + 3] = f.w;
    }
    __syncthreads();
    for (int u = threadIdx.x; u < 512; u += 256) {
        const int n  = u >> 3;
        const int kg = u & 7;
        union { ushort us[8]; uint4 u4; } o;
        #pragma unroll
        for (int j = 0; j < 8; ++j) {
            _Float16 h = (_Float16)(sT[kg * 8 + j][n] * ws);
            o.us[j] = *(ushort*)&h;
        }
        *(uint4*)(Wt + (size_t)(n0 + n) * DIM + k0 + kg * 8) = o.u4;
    }
}

// ---------------------------------------------------------------------------
// fp16 MFMA GEMM 128x128 (round-8 proven): C = A @ Wt^T + bias*bscale
// ---------------------------------------------------------------------------
__device__ __forceinline__ void gemm_body128(
    const ushort* __restrict__ A, const ushort* __restrict__ Bt,
    const float* __restrict__ bias, float bscale, ushort* __restrict__ C, int M)
{
    __shared__ _Float16 sA[128][72];
    __shared__ _Float16 sB[128][72];

    const int tid  = threadIdx.x;
    const int row0 = blockIdx.x * 128;
    const int col0 = blockIdx.y * 128;
    const int wave = tid >> 6, lane = tid & 63;
    const int wr = wave >> 1, wc = wave & 1;
    const int fr = lane & 15, fq = lane >> 4;

    f32x4 acc[4][4];
    #pragma unroll
    for (int n = 0; n < 4; ++n) {
        const float bb = bias[col0 + wc * 64 + n * 16 + fr] * bscale;
        #pragma unroll
        for (int m = 0; m < 4; ++m) acc[m][n] = (f32x4){bb, bb, bb, bb};
    }

    for (int k0 = 0; k0 < 512; k0 += 64) {
        __syncthreads();
        #pragma unroll
        for (int it = 0; it < 8; ++it) {
            const int u  = tid + it * 256;
            const int r  = (u >> 3) & 127;
            const int cc = u & 7;
            if (u < 1024) {
                int gr = row0 + r; if (gr >= M) gr = M - 1;
                *(uint4*)&sA[r][cc * 8] =
                    *(const uint4*)(A + (size_t)gr * 512 + k0 + cc * 8);
            } else {
                *(uint4*)&sB[r][cc * 8] =
                    *(const uint4*)(Bt + (size_t)(col0 + r) * 512 + k0 + cc * 8);
            }
        }
        __syncthreads();
        #pragma unroll
        for (int kk = 0; kk < 2; ++kk) {
            f16x8 a[4], b[4];
            #pragma unroll
            for (int m = 0; m < 4; ++m)
                a[m] = *(const f16x8*)&sA[wr * 64 + m * 16 + fr][kk * 32 + fq * 8];
            #pragma unroll
            for (int n = 0; n < 4; ++n)
                b[n] = *(const f16x8*)&sB[wc * 64 + n * 16 + fr][kk * 32 + fq * 8];
            #pragma unroll
            for (int m = 0; m < 4; ++m)
                #pragma unroll
                for (int n = 0; n < 4; ++n)
                    acc[m][n] = __builtin_amdgcn_mfma_f32_16x16x32_f16(
                        a[m], b[n], acc[m][n], 0, 0, 0);
        }
    }

    #pragma unroll
    for (int m = 0; m < 4; ++m)
        #pragma unroll
        for (int n = 0; n < 4; ++n)
            #pragma unroll
            for (int j = 0; j < 4; ++j) {
                const int row = row0 + wr * 64 + m * 16 + fq * 4 + j;
                const int col = col0 + wc * 64 + n * 16 + fr;
                if (row < M) {
                    _Float16 h = (_Float16)acc[m][n][j];
                    C[(size_t)row * 512 + col] = *(ushort*)&h;
                }
            }
}

__global__ __launch_bounds__(256) void gemm_qkv(
    const ushort* __restrict__ Xq, const ushort* __restrict__ Xk,
    const ushort* __restrict__ Xv,
    const ushort* __restrict__ Wtq, const ushort* __restrict__ Wtk,
    const ushort* __restrict__ Wtv,
    const float* __restrict__ bq, const float* __restrict__ bk,
    const float* __restrict__ bv,
    ushort* __restrict__ Qc, ushort* __restrict__ Kc, ushort* __restrict__ Vc)
{
    const int w = blockIdx.z;
    const ushort* A  = w == 0 ? Xq  : (w == 1 ? Xk  : Xv);
    const ushort* Bt = w == 0 ? Wtq : (w == 1 ? Wtk : Wtv);
    const float*  bi = w == 0 ? bq  : (w == 1 ? bk  : bv);
    ushort*       Cc = w == 0 ? Qc  : (w == 1 ? Kc  : Vc);
    gemm_body128(A, Bt, bi, (w == 0) ? QSCALE : 1.0f, Cc, MROWS);
}

// ---------------------------------------------------------------------------
// Out projection, 64x128 tiles (256 blocks = full GPU), fp32 output + bias
// ---------------------------------------------------------------------------
__global__ __launch_bounds__(256) void gemm_out64(
    const ushort* __restrict__ A, const ushort* __restrict__ Bt,
    const float* __restrict__ bias, float* __restrict__ C)
{
    __shared__ _Float16 sA[64][72];
    __shared__ _Float16 sB[128][72];

    const int tid  = threadIdx.x;
    const int row0 = blockIdx.x * 64;
    const int col0 = blockIdx.y * 128;
    const int wave = tid >> 6, lane = tid & 63;
    const int wr = wave >> 1, wc = wave & 1;    // wr: 32-row half, wc: 64-col half
    const int fr = lane & 15, fq = lane >> 4;

    f32x4 acc[2][4];
    #pragma unroll
    for (int n = 0; n < 4; ++n) {
        const float bb = bias[col0 + wc * 64 + n * 16 + fr];
        #pragma unroll
        for (int m = 0; m < 2; ++m) acc[m][n] = (f32x4){bb, bb, bb, bb};
    }

    for (int k0 = 0; k0 < 512; k0 += 64) {
        __syncthreads();
        #pragma unroll
        for (int it = 0; it < 6; ++it) {
            const int u  = tid + it * 256;      // 0..1535
            const int cc = u & 7;
            if (u < 512) {
                const int r = u >> 3;
                *(uint4*)&sA[r][cc * 8] =
                    *(const uint4*)(A + (size_t)(row0 + r) * 512 + k0 + cc * 8);
            } else {
                const int r = (u - 512) >> 3;
                *(uint4*)&sB[r][cc * 8] =
                    *(const uint4*)(Bt + (size_t)(col0 + r) * 512 + k0 + cc * 8);
            }
        }
        __syncthreads();
        #pragma unroll
        for (int kk = 0; kk < 2; ++kk) {
            f16x8 a[2], b[4];
            #pragma unroll
            for (int m = 0; m < 2; ++m)
                a[m] = *(const f16x8*)&sA[wr * 32 + m * 16 + fr][kk * 32 + fq * 8];
            #pragma unroll
            for (int n = 0; n < 4; ++n)
                b[n] = *(const f16x8*)&sB[wc * 64 + n * 16 + fr][kk * 32 + fq * 8];
            #pragma unroll
            for (int m = 0; m < 2; ++m)
                #pragma unroll
                for (int n = 0; n < 4; ++n)
                    acc[m][n] = __builtin_amdgcn_mfma_f32_16x16x32_f16(
                        a[m], b[n], acc[m][n], 0, 0, 0);
        }
    }

    #pragma unroll
    for (int m = 0; m < 2; ++m)
        #pragma unroll
        for (int n = 0; n < 4; ++n)
            #pragma unroll
            for (int j = 0; j < 4; ++j) {
                const int row = row0 + wr * 32 + m * 16 + fq * 4 + j;
                const int col = col0 + wc * 64 + n * 16 + fr;
                C[(size_t)row * 512 + col] = acc[m][n][j];
            }
}

// ---------------------------------------------------------------------------
// MFMA flash attention: 8 waves x 16 queries (QT=128).
// Q pre-scaled (QSCALE folded into Wq/bq) -> raw-score softmax.
// Group 0 (mem + first window chunk), then contiguous window groups two at a
// time with one merged 64-key softmax (chain halved, rescale amortized).
// ---------------------------------------------------------------------------
__global__ __launch_bounds__(512, 4) void attn_mfma(
    const ushort* __restrict__ Q, const ushort* __restrict__ K,
    const ushort* __restrict__ V, ushort* __restrict__ ctx)
{
    const int tid  = threadIdx.x;
    const int tile = blockIdx.x, h = blockIdx.y, b = blockIdx.z;
    const int wave = tid >> 6, lane = tid & 63;
    const int fr = lane & 15, fq = lane >> 4;
    const int fq8 = fq * 8, fq4 = fq * 4;

    const int i0  = MEMN + tile * QT;
    const int klo = max(MEMN, i0 - WHALF);
    const int khi = min(T_TOT - 1, i0 + QT - 1 + WHALF);
    const int total  = MEMN + khi - klo + 1;           // <= 401
    const int ustage = (total + 31) & ~31;             // pad to 32

    __shared__ ushort sK[MAXU][KSTR];                  // 33.3 KiB
    __shared__ ushort sVt[HEAD_DIM][VSTR];             // 27.1 KiB

    const size_t hbase = (size_t)b * T_TOT * DIM + (size_t)h * HEAD_DIM;

    // ---- stage K rows; chunk rotated by (c+u)&3 for bank spread ----
    for (int idx = tid; idx < ustage * 4; idx += 512) {
        const int u = idx >> 2, c = idx & 3;
        const int cc = (c + u) & 3;
        uint4 val = {0, 0, 0, 0};
        if (u < total) {
            const int g = (u < MEMN) ? u : klo + u - MEMN;
            val = *(const uint4*)(K + hbase + (size_t)g * DIM + cc * 8);
        }
        *(uint4*)&sK[u][cc * 8] = val;
    }
    // ---- stage V transposed into PERMUTED key columns ----
    for (int idx = tid; idx < (ustage / 2) * 4; idx += 512) {
        const int pr = idx >> 2;                       // key-pair index
        const int u2 = pr * 2, c = idx & 3;
        union { uint4 q4; ushort us[8]; } r0, r1;
        r0.q4 = (uint4){0, 0, 0, 0};
        r1.q4 = (uint4){0, 0, 0, 0};
        if (u2 < total) {
            const int g0 = (u2 < MEMN) ? u2 : klo + u2 - MEMN;
            r0.q4 = *(const uint4*)(V + hbase + (size_t)g0 * DIM + c * 8);
        }
        if (u2 + 1 < total) {
            const int g1 = (u2 + 1 < MEMN) ? u2 + 1 : klo + u2 + 1 - MEMN;
            r1.q4 = *(const uint4*)(V + hbase + (size_t)g1 * DIM + c * 8);
        }
        const int g  = u2 & 31, gb = u2 & ~31;
        const int w  = (g < 16) ? ((g >> 2) * 4 + ((g >> 1) & 1))
                                : (((g - 16) >> 2) * 4 + 2 + (((g - 16) >> 1) & 1));
        const int col = gb + w * 2;
        #pragma unroll
        for (int ii = 0; ii < 8; ++ii) {
            const int i = (ii + pr + 2 * c) & 7;
            const uint wv = (uint)r0.us[i] | ((uint)r1.us[i] << 16);
            *(uint*)&sVt[c * 8 + i][col] = wv;
        }
    }

    // ---- Q fragment (pre-scaled): lane holds Q[q=fr][d=fq*8..+7] ----
    const int iq = i0 + wave * 16 + fr;
    const f16x8 qf = *(const f16x8*)(Q + (size_t)(b * T_TOT + iq) * DIM
                                     + h * HEAD_DIM + fq8);

    const int ulo  = max(iq - WHALF - klo, 0) + MEMN;
    const int uhi  = min(iq + WHALF, khi) - klo + MEMN;
    const int span = uhi - ulo;
    const int iw0  = i0 + wave * 16;
    const int ulo_minw = max(iw0 - WHALF - klo, 0) + MEMN;
    const int ulo_maxw = max(iw0 + 15 - WHALF - klo, 0) + MEMN;
    const int uhi_minw = min(iw0 + WHALF, khi) - klo + MEMN;
    const int uhi_maxw = min(iw0 + 15 + WHALF, khi) - klo + MEMN;
    const int glo = max(1, ulo_minw >> 5);
    const int ghi = uhi_maxw >> 5;

    __syncthreads();

    const float NEGINF = -__builtin_huge_valf();
    float mns = 0.0f;                                  // running raw max
    float l   = 0.f;
    f32x4 oc0 = {0, 0, 0, 0}, oc1 = {0, 0, 0, 0};

    // ---------------- group 0: mem rows (unmasked) + rows 16-31 ----------------
    {
        const f16x8 kfA = *(const f16x8*)&sK[fr][fq8];
        const f16x8 kfB = *(const f16x8*)&sK[16 + fr][fq8];
        f32x4 sA = {0, 0, 0, 0}, sB = {0, 0, 0, 0};
        sA = __builtin_amdgcn_mfma_f32_16x16x32_f16(kfA, qf, sA, 0, 0, 0);
        sB = __builtin_amdgcn_mfma_f32_16x16x32_f16(kfB, qf, sB, 0, 0, 0);
        if (!(16 >= ulo_maxw && 31 <= uhi_minw)) {
            #pragma unroll
            for (int j = 0; j < 4; ++j) {
                const uint uu = (uint)(16 + fq4 + j - ulo);
                sB[j] = (uu <= (uint)span) ? sB[j] : NEGINF;
            }
        }
        float mx = fmaxf(fmaxf(fmaxf(sA[0], sA[1]), fmaxf(sA[2], sA[3])),
                         fmaxf(fmaxf(sB[0], sB[1]), fmaxf(sB[2], sB[3])));
        mx = fmaxf(mx, __shfl_xor(mx, 16));
        mx = fmaxf(mx, __shfl_xor(mx, 32));
        if (!__all(mx <= mns)) {
            const float mn2   = fmaxf(mns, mx);
            const float alpha = __expf(mns - mn2);
            l *= alpha;
            #pragma unroll
            for (int j = 0; j < 4; ++j) { oc0[j] *= alpha; oc1[j] *= alpha; }
            mns = mn2;
        }
        const float p0 = __expf(sA[0] - mns), p1 = __expf(sA[1] - mns);
        const float p2 = __expf(sA[2] - mns), p3 = __expf(sA[3] - mns);
        const float p4 = __expf(sB[0] - mns), p5 = __expf(sB[1] - mns);
        const float p6 = __expf(sB[2] - mns), p7 = __expf(sB[3] - mns);
        l += ((p0 + p1) + (p2 + p3)) + ((p4 + p5) + (p6 + p7));
        union { f16raw2 h2; uint u; } c0, c1, c2, c3;
        c0.h2 = __builtin_amdgcn_cvt_pkrtz(p0, p1);
        c1.h2 = __builtin_amdgcn_cvt_pkrtz(p2, p3);
        c2.h2 = __builtin_amdgcn_cvt_pkrtz(p4, p5);
        c3.h2 = __builtin_amdgcn_cvt_pkrtz(p6, p7);
        union { uint u[4]; f16x8 h; } P;
        P.u[0] = c0.u; P.u[1] = c1.u; P.u[2] = c2.u; P.u[3] = c3.u;
        const f16x8 va0 = *(const f16x8*)&sVt[fr][fq8];
        const f16x8 va1 = *(const f16x8*)&sVt[fr + 16][fq8];
        oc0 = __builtin_amdgcn_mfma_f32_16x16x32_f16(va0, P.h, oc0, 0, 0, 0);
        oc1 = __builtin_amdgcn_mfma_f32_16x16x32_f16(va1, P.h, oc1, 0, 0, 0);
    }

    // ---------------- window groups, two per iteration ----------------
    int g = glo;
    for (; g + 1 <= ghi; g += 2) {
        const int ua = g * 32, ub2 = ua + 32;
        const f16x8 kf0 = *(const f16x8*)&sK[ua + fr][fq8];
        const f16x8 kf1 = *(const f16x8*)&sK[ua + 16 + fr][fq8];
        const f16x8 kf2 = *(const f16x8*)&sK[ub2 + fr][fq8];
        const f16x8 kf3 = *(const f16x8*)&sK[ub2 + 16 + fr][fq8];
        f32x4 s0 = {0,0,0,0}, s1 = {0,0,0,0}, s2 = {0,0,0,0}, s3 = {0,0,0,0};
        s0 = __builtin_amdgcn_mfma_f32_16x16x32_f16(kf0, qf, s0, 0, 0, 0);
        s1 = __builtin_amdgcn_mfma_f32_16x16x32_f16(kf1, qf, s1, 0, 0, 0);
        s2 = __builtin_amdgcn_mfma_f32_16x16x32_f16(kf2, qf, s2, 0, 0, 0);
        s3 = __builtin_amdgcn_mfma_f32_16x16x32_f16(kf3, qf, s3, 0, 0, 0);
        #pragma unroll
        for (int cch = 0; cch < 4; ++cch) {
            const int base = ua + cch * 16;
            f32x4& sc = cch == 0 ? s0 : (cch == 1 ? s1 : (cch == 2 ? s2 : s3));
            if (!(base >= ulo_maxw && base + 15 <= uhi_minw)) {
                #pragma unroll
                for (int j = 0; j < 4; ++j) {
                    const uint uu = (uint)(base + fq4 + j - ulo);
                    sc[j] = (uu <= (uint)span) ? sc[j] : NEGINF;
                }
            }
        }
        float mxA = fmaxf(fmaxf(fmaxf(s0[0], s0[1]), fmaxf(s0[2], s0[3])),
                          fmaxf(fmaxf(s1[0], s1[1]), fmaxf(s1[2], s1[3])));
        float mxB = fmaxf(fmaxf(fmaxf(s2[0], s2[1]), fmaxf(s2[2], s2[3])),
                          fmaxf(fmaxf(s3[0], s3[1]), fmaxf(s3[2], s3[3])));
        float mx = fmaxf(mxA, mxB);
        mx = fmaxf(mx, __shfl_xor(mx, 16));
        mx = fmaxf(mx, __shfl_xor(mx, 32));
        if (!__all(mx <= mns)) {
            const float mn2   = fmaxf(mns, mx);
            const float alpha = __expf(mns - mn2);
            l *= alpha;
            #pragma unroll
            for (int j = 0; j < 4; ++j) { oc0[j] *= alpha; oc1[j] *= alpha; }
            mns = mn2;
        }
        const float a0 = __expf(s0[0] - mns), a1 = __expf(s0[1] - mns);
        const float a2 = __expf(s0[2] - mns), a3 = __expf(s0[3] - mns);
        const float a4 = __expf(s1[0] - mns), a5 = __expf(s1[1] - mns);
        const float a6 = __expf(s1[2] - mns), a7 = __expf(s1[3] - mns);
        const float b0 = __expf(s2[0] - mns), b1 = __expf(s2[1] - mns);
        const float b2 = __expf(s2[2] - mns), b3 = __expf(s2[3] - mns);
        const float b4 = __expf(s3[0] - mns), b5 = __expf(s3[1] - mns);
        const float b6 = __expf(s3[2] - mns), b7 = __expf(s3[3] - mns);
        l += (((a0 + a1) + (a2 + a3)) + ((a4 + a5) + (a6 + a7)))
           + (((b0 + b1) + (b2 + b3)) + ((b4 + b5) + (b6 + b7)));
        union { f16raw2 h2; uint u; } d0, d1, d2, d3, e0, e1, e2, e3;
        d0.h2 = __builtin_amdgcn_cvt_pkrtz(a0, a1);
        d1.h2 = __builtin_amdgcn_cvt_pkrtz(a2, a3);
        d2.h2 = __builtin_amdgcn_cvt_pkrtz(a4, a5);
        d3.h2 = __builtin_amdgcn_cvt_pkrtz(a6, a7);
        e0.h2 = __builtin_amdgcn_cvt_pkrtz(b0, b1);
        e1.h2 = __builtin_amdgcn_cvt_pkrtz(b2, b3);
        e2.h2 = __builtin_amdgcn_cvt_pkrtz(b4, b5);
        e3.h2 = __builtin_amdgcn_cvt_pkrtz(b6, b7);
        union { uint u[4]; f16x8 h; } P0, P1;
        P0.u[0] = d0.u; P0.u[1] = d1.u; P0.u[2] = d2.u; P0.u[3] = d3.u;
        P1.u[0] = e0.u; P1.u[1] = e1.u; P1.u[2] = e2.u; P1.u[3] = e3.u;
        const f16x8 va0a = *(const f16x8*)&sVt[fr][ua + fq8];
        const f16x8 va1a = *(const f16x8*)&sVt[fr + 16][ua + fq8];
        const f16x8 va0b = *(const f16x8*)&sVt[fr][ub2 + fq8];
        const f16x8 va1b = *(const f16x8*)&sVt[fr + 16][ub2 + fq8];
        oc0 = __builtin_amdgcn_mfma_f32_16x16x32_f16(va0a, P0.h, oc0, 0, 0, 0);
        oc1 = __builtin_amdgcn_mfma_f32_16x16x32_f16(va1a, P0.h, oc1, 0, 0, 0);
        oc0 = __builtin_amdgcn_mfma_f32_16x16x32_f16(va0b, P1.h, oc0, 0, 0, 0);
        oc1 = __builtin_amdgcn_mfma_f32_16x16x32_f16(va1b, P1.h, oc1, 0, 0, 0);
    }
    // odd tail group
    if (g <= ghi) {
        const int ua = g * 32;
        const f16x8 kf0 = *(const f16x8*)&sK[ua + fr][fq8];
        const f16x8 kf1 = *(const f16x8*)&sK[ua + 16 + fr][fq8];
        f32x4 s0 = {0,0,0,0}, s1 = {0,0,0,0};
        s0 = __builtin_amdgcn_mfma_f32_16x16x32_f16(kf0, qf, s0, 0, 0, 0);
        s1 = __builtin_amdgcn_mfma_f32_16x16x32_f16(kf1, qf, s1, 0, 0, 0);
        #pragma unroll
        for (int cch = 0; cch < 2; ++cch) {
            const int base = ua + cch * 16;
            f32x4& sc = cch == 0 ? s0 : s1;
            if (!(base >= ulo_maxw && base + 15 <= uhi_minw)) {
                #pragma unroll
                for (int j = 0; j < 4; ++j) {
                    const uint uu = (uint)(base + fq4 + j - ulo);
                    sc[j] = (uu <= (uint)span) ? sc[j] : NEGINF;
                }
            }
        }
        float mx = fmaxf(fmaxf(fmaxf(s0[0], s0[1]), fmaxf(s0[2], s0[3])),
                         fmaxf(fmaxf(s1[0], s1[1]), fmaxf(s1[2], s1[3])));
        mx = fmaxf(mx, __shfl_xor(mx, 16));
        mx = fmaxf(mx, __shfl_xor(mx, 32));
        if (!__all(mx <= mns)) {
            const float mn2   = fmaxf(mns, mx);
            const float alpha = __expf(mns - mn2);
            l *= alpha;
            #pragma unroll
            for (int j = 0; j < 4; ++j) { oc0[j] *= alpha; oc1[j] *= alpha; }
            mns = mn2;
        }
        const float p0 = __expf(s0[0] - mns), p1 = __expf(s0[1] - mns);
        const float p2 = __expf(s0[2] - mns), p3 = __expf(s0[3] - mns);
        const float p4 = __expf(s1[0] - mns), p5 = __expf(s1[1] - mns);
        const float p6 = __expf(s1[2] - mns), p7 = __expf(s1[3] - mns);
        l += ((p0 + p1) + (p2 + p3)) + ((p4 + p5) + (p6 + p7));
        union { f16raw2 h2; uint u; } c0, c1, c2, c3;
        c0.h2 = __builtin_amdgcn_cvt_pkrtz(p0, p1);
        c1.h2 = __builtin_amdgcn_cvt_pkrtz(p2, p3);
        c2.h2 = __builtin_amdgcn_cvt_pkrtz(p4, p5);
        c3.h2 = __builtin_amdgcn_cvt_pkrtz(p6, p7);
        union { uint u[4]; f16x8 h; } P;
        P.u[0] = c0.u; P.u[1] = c1.u; P.u[2] = c2.u; P.u[3] = c3.u;
        const f16x8 va0 = *(const f16x8*)&sVt[fr][ua + fq8];
        const f16x8 va1 = *(const f16x8*)&sVt[fr + 16][ua + fq8];
        oc0 = __builtin_amdgcn_mfma_f32_16x16x32_f16(va0, P.h, oc0, 0, 0, 0);
        oc1 = __builtin_amdgcn_mfma_f32_16x16x32_f16(va1, P.h, oc1, 0, 0, 0);
    }

    // ---- finalize ----
    l += __shfl_xor(l, 16);
    l += __shfl_xor(l, 32);
    const float inv = 1.0f / l;
    union { f16raw2 h2; uint u; } w00, w01, w10, w11;
    w00.h2 = __builtin_amdgcn_cvt_pkrtz(oc0[0] * inv, oc0[1] * inv);
    w01.h2 = __builtin_amdgcn_cvt_pkrtz(oc0[2] * inv, oc0[3] * inv);
    w10.h2 = __builtin_amdgcn_cvt_pkrtz(oc1[0] * inv, oc1[1] * inv);
    w11.h2 = __builtin_amdgcn_cvt_pkrtz(oc1[2] * inv, oc1[3] * inv);
    ushort* cp = ctx + ((size_t)b * SEQ + (iq - MEMN)) * DIM
               + h * HEAD_DIM + fq4;
    *(uint2*)cp        = (uint2){w00.u, w01.u};
    *(uint2*)(cp + 16) = (uint2){w10.u, w11.u};
}

// ---------------------------------------------------------------------------
extern "C" void kernel_launch(void* const* d_in, const int* in_sizes, int n_in,
                              void* d_out, int out_size, void* d_ws, size_t ws_size,
                              hipStream_t stream) {
    const float* q    = (const float*)d_in[0];
    const float* k    = (const float*)d_in[1];
    const float* v    = (const float*)d_in[2];
    const float* memp = (const float*)d_in[3];
    const float* Wq   = (const float*)d_in[4];
    const float* bq   = (const float*)d_in[5];
    const float* Wk   = (const float*)d_in[6];
    const float* bk   = (const float*)d_in[7];
    const float* Wv   = (const float*)d_in[8];
    const float* bv   = (const float*)d_in[9];
    const float* Wo   = (const float*)d_in[10];
    const float* bo   = (const float*)d_in[11];
    float* out = (float*)d_out;

    const size_t NX = (size_t)MROWS * DIM;
    const size_t NW = (size_t)DIM * DIM;
    const size_t NC = (size_t)OROWS * DIM;

    ushort* p   = (ushort*)d_ws;
    ushort* Xq  = p;            p += NX;
    ushort* Xk  = p;            p += NX;
    ushort* Xv  = p;            p += NX;
    ushort* Qc  = p;            p += NX;
    ushort* Kc  = p;            p += NX;
    ushort* Vc  = p;            p += NX;
    ushort* Wtq = p;            p += NW;
    ushort* Wtk = p;            p += NW;
    ushort* Wtv = p;            p += NW;
    ushort* Wto = p;            p += NW;
    ushort* Cc  = p;            p += NC;               // ~31.7 MB total

    dim3 gp((MROWS * DIM / 8 + 255) / 256, 1, 7);
    prep_cvt<<<gp, 256, 0, stream>>>(q, k, v, memp, Wq, Wk, Wv, Wo,
                                     Xq, Xk, Xv, Wtq, Wtk, Wtv, Wto);

    dim3 g1((MROWS + 127) / 128, 4, 3);
    gemm_qkv<<<g1, 256, 0, stream>>>(Xq, Xk, Xv, Wtq, Wtk, Wtv,
                                     bq, bk, bv, Qc, Kc, Vc);

    dim3 g2(SEQ / QT, NUM_HEADS, BATCH);
    attn_mfma<<<g2, 512, 0, stream>>>(Qc, Kc, Vc, Cc);

    dim3 g3(OROWS / 64, 4, 1);
    gemm_out64<<<g3, 256, 0, stream>>>(Cc, Wto, bo, out);
}

// Round 14
// 65.340 us; speedup vs baseline: 1.4550x; 1.2347x over previous
//
#include <hip/hip_runtime.h>
#include <hip/hip_bf16.h>
#include <hip/hip_fp16.h>

#define DIM 512
#define NUM_HEADS 16
#define HEAD_DIM 32
#define WHALF 128
#define MEMN 16
#define SEQ 2048
#define BATCH 2
#define T_TOT (SEQ + MEMN)                 // 2064
#define MROWS (BATCH * T_TOT)              // 4128
#define OROWS (BATCH * SEQ)                // 4096
#define QT 128                             // queries per attn block (8 waves)
#define MAXU 416                           // pad32 of max union window (401)
#define KSTR 40                            // sK row stride (halves), 80B
#define VPLANE (MAXU * 16 * 2)             // bytes per sV plane = 13312

typedef _Float16 f16x8 __attribute__((ext_vector_type(8)));
typedef __fp16   f16raw2 __attribute__((ext_vector_type(2)));   // cvt_pkrtz return
typedef float    f32x4 __attribute__((ext_vector_type(4)));
typedef uint     u32x2 __attribute__((ext_vector_type(2)));

#define QSCALE 0.17677669529663687f        // 1/sqrt(32), folded into Wq/bq

// gfx950 LDS transpose read: lane l, elem j <- lds[(l&15) + j*16 + (l>>4)*64]
// (half-units, relative to the 16-lane group's region; addr = base + 8*lane).
__device__ __forceinline__ u32x2 tr64(uint addr) {
    u32x2 r;
    asm volatile("ds_read_b64_tr_b16 %0, %1" : "=v"(r) : "v"(addr));
    return r;
}

// ---------------------------------------------------------------------------
// Merged prep: z in [0,3): fp16 X matrices; z in [3,7): Wt[n][k] = W[k][n].
// Wq pre-scaled by QSCALE so attention needs no score scaling.
// ---------------------------------------------------------------------------
__global__ __launch_bounds__(256) void prep_cvt(
    const float* __restrict__ q, const float* __restrict__ k,
    const float* __restrict__ v, const float* __restrict__ memp,
    const float* __restrict__ Wq, const float* __restrict__ Wk,
    const float* __restrict__ Wv, const float* __restrict__ Wo,
    ushort* __restrict__ Xq, ushort* __restrict__ Xk, ushort* __restrict__ Xv,
    ushort* __restrict__ Wtq, ushort* __restrict__ Wtk,
    ushort* __restrict__ Wtv, ushort* __restrict__ Wto)
{
    const int z = blockIdx.z;
    if (z < 3) {
        const float* X = z == 0 ? q : (z == 1 ? k : v);
        ushort*     Xc = z == 0 ? Xq : (z == 1 ? Xk : Xv);
        const int gid  = blockIdx.x * 256 + threadIdx.x;
        const int base = gid * 8;
        if (base >= MROWS * DIM) return;
        const int row = base >> 9;
        const int c   = base & 511;
        const int b   = row / T_TOT;
        const int t   = row - b * T_TOT;
        const float* src = (t < MEMN)
            ? (memp + (size_t)t * DIM + c)
            : (X + ((size_t)b * SEQ + (t - MEMN)) * DIM + c);
        const float4 a0 = *(const float4*)src;
        const float4 a1 = *(const float4*)(src + 4);
        union { _Float16 hh[8]; uint4 u4; } o;
        o.hh[0] = (_Float16)a0.x; o.hh[1] = (_Float16)a0.y;
        o.hh[2] = (_Float16)a0.z; o.hh[3] = (_Float16)a0.w;
        o.hh[4] = (_Float16)a1.x; o.hh[5] = (_Float16)a1.y;
        o.hh[6] = (_Float16)a1.z; o.hh[7] = (_Float16)a1.w;
        *(uint4*)(Xc + (size_t)row * DIM + c) = o.u4;
        return;
    }
    if (blockIdx.x >= 64) return;
    const int w = z - 3;
    const float* W  = w == 0 ? Wq  : (w == 1 ? Wk  : (w == 2 ? Wv  : Wo));
    ushort*     Wt  = w == 0 ? Wtq : (w == 1 ? Wtk : (w == 2 ? Wtv : Wto));
    const float ws  = (w == 0) ? QSCALE : 1.0f;

    __shared__ float sT[64][65];
    const int n0 = (blockIdx.x & 7) * 64;
    const int k0 = (blockIdx.x >> 3) * 64;

    for (int e = threadIdx.x; e < 1024; e += 256) {
        const int r  = e >> 4;
        const int c4 = e & 15;
        const float4 f = *(const float4*)(W + (size_t)(k0 + r) * DIM + n0 + c4 * 4);
        sT[r][c4 * 4 + 0] = f.x;
        sT[r][c4 * 4 + 1] = f.y;
        sT[r][c4 * 4 + 2] = f.z;
        sT[r][c4 * 4 + 3] = f.w;
    }
    __syncthreads();
    for (int u = threadIdx.x; u < 512; u += 256) {
        const int n  = u >> 3;
        const int kg = u & 7;
        union { ushort us[8]; uint4 u4; } o;
        #pragma unroll
        for (int j = 0; j < 8; ++j) {
            _Float16 h = (_Float16)(sT[kg * 8 + j][n] * ws);
            o.us[j] = *(ushort*)&h;
        }
        *(uint4*)(Wt + (size_t)(n0 + n) * DIM + k0 + kg * 8) = o.u4;
    }
}

// ---------------------------------------------------------------------------
// fp16 MFMA GEMM, 64x128 tile (load-balanced): C = A @ Wt^T + bias*bscale
// ---------------------------------------------------------------------------
template<bool OUT_HALF>
__device__ __forceinline__ void gemm_body64(
    const ushort* __restrict__ A, const ushort* __restrict__ Bt,
    const float* __restrict__ bias, float bscale, void* __restrict__ C, int M)
{
    __shared__ _Float16 sA[64][72];
    __shared__ _Float16 sB[128][72];

    const int tid  = threadIdx.x;
    const int row0 = blockIdx.x * 64;
    const int col0 = blockIdx.y * 128;
    const int wave = tid >> 6, lane = tid & 63;
    const int wr = wave >> 1, wc = wave & 1;
    const int fr = lane & 15, fq = lane >> 4;

    f32x4 acc[2][4];
    #pragma unroll
    for (int n = 0; n < 4; ++n) {
        const float bb = bias[col0 + wc * 64 + n * 16 + fr] * bscale;
        #pragma unroll
        for (int m = 0; m < 2; ++m) acc[m][n] = (f32x4){bb, bb, bb, bb};
    }

    for (int k0 = 0; k0 < 512; k0 += 64) {
        __syncthreads();
        #pragma unroll
        for (int it = 0; it < 6; ++it) {
            const int u  = tid + it * 256;      // 0..1535
            const int cc = u & 7;
            if (u < 512) {
                const int r = u >> 3;
                int gr = row0 + r; if (gr >= M) gr = M - 1;
                *(uint4*)&sA[r][cc * 8] =
                    *(const uint4*)(A + (size_t)gr * 512 + k0 + cc * 8);
            } else {
                const int r = (u - 512) >> 3;
                *(uint4*)&sB[r][cc * 8] =
                    *(const uint4*)(Bt + (size_t)(col0 + r) * 512 + k0 + cc * 8);
            }
        }
        __syncthreads();
        #pragma unroll
        for (int kk = 0; kk < 2; ++kk) {
            f16x8 a[2], b[4];
            #pragma unroll
            for (int m = 0; m < 2; ++m)
                a[m] = *(const f16x8*)&sA[wr * 32 + m * 16 + fr][kk * 32 + fq * 8];
            #pragma unroll
            for (int n = 0; n < 4; ++n)
                b[n] = *(const f16x8*)&sB[wc * 64 + n * 16 + fr][kk * 32 + fq * 8];
            #pragma unroll
            for (int m = 0; m < 2; ++m)
                #pragma unroll
                for (int n = 0; n < 4; ++n)
                    acc[m][n] = __builtin_amdgcn_mfma_f32_16x16x32_f16(
                        a[m], b[n], acc[m][n], 0, 0, 0);
        }
    }

    #pragma unroll
    for (int m = 0; m < 2; ++m)
        #pragma unroll
        for (int n = 0; n < 4; ++n)
            #pragma unroll
            for (int j = 0; j < 4; ++j) {
                const int row = row0 + wr * 32 + m * 16 + fq * 4 + j;
                const int col = col0 + wc * 64 + n * 16 + fr;
                if (row < M) {
                    if (OUT_HALF) {
                        _Float16 h = (_Float16)acc[m][n][j];
                        ((ushort*)C)[(size_t)row * 512 + col] = *(ushort*)&h;
                    } else {
                        ((float*)C)[(size_t)row * 512 + col] = acc[m][n][j];
                    }
                }
            }
}

__global__ __launch_bounds__(256) void gemm_qkv(
    const ushort* __restrict__ Xq, const ushort* __restrict__ Xk,
    const ushort* __restrict__ Xv,
    const ushort* __restrict__ Wtq, const ushort* __restrict__ Wtk,
    const ushort* __restrict__ Wtv,
    const float* __restrict__ bq, const float* __restrict__ bk,
    const float* __restrict__ bv,
    ushort* __restrict__ Qc, ushort* __restrict__ Kc, ushort* __restrict__ Vc)
{
    const int w = blockIdx.z;
    const ushort* A  = w == 0 ? Xq  : (w == 1 ? Xk  : Xv);
    const ushort* Bt = w == 0 ? Wtq : (w == 1 ? Wtk : Wtv);
    const float*  bi = w == 0 ? bq  : (w == 1 ? bk  : bv);
    ushort*       Cc = w == 0 ? Qc  : (w == 1 ? Kc  : Vc);
    gemm_body64<true>(A, Bt, bi, (w == 0) ? QSCALE : 1.0f, Cc, MROWS);
}

__global__ __launch_bounds__(256) void gemm_out64(
    const ushort* __restrict__ A, const ushort* __restrict__ Bt,
    const float* __restrict__ bias, float* __restrict__ C)
{
    gemm_body64<false>(A, Bt, bias, 1.0f, C, OROWS);
}

// ---------------------------------------------------------------------------
// MFMA flash attention: 8 waves x 16 queries (QT=128), 32-key groups.
// QK^T swapped (A=K, B=Q). PV K=32: A-operand = V^T fragments delivered by
// ds_read_b64_tr_b16 from two linear d-half planes sV[2][MAXU][16] — the key
// permutation (k'=8fq+e -> key e<4 ? 4fq+e : 16+4fq+(e-4)) is exactly the
// tr-read's lane mapping, so P (QK scores) feeds PV with ZERO cross-lane ops
// and V staging is plain linear b128 writes (conflict-free).
// ---------------------------------------------------------------------------
__global__ __launch_bounds__(512, 4) void attn_mfma(
    const ushort* __restrict__ Q, const ushort* __restrict__ K,
    const ushort* __restrict__ V, ushort* __restrict__ ctx)
{
    const int tid  = threadIdx.x;
    const int tile = blockIdx.x, h = blockIdx.y, b = blockIdx.z;
    const int wave = tid >> 6, lane = tid & 63;
    const int fr = lane & 15, fq = lane >> 4;
    const int fq8 = fq * 8, fq4 = fq * 4;

    const int i0  = MEMN + tile * QT;
    const int klo = max(MEMN, i0 - WHALF);
    const int khi = min(T_TOT - 1, i0 + QT - 1 + WHALF);
    const int total  = MEMN + khi - klo + 1;           // <= 401
    const int ustage = (total + 31) & ~31;             // pad to 32

    __shared__ ushort sK[MAXU][KSTR];                  // 33.3 KiB
    __shared__ ushort sV[2][MAXU][16];                 // 26.0 KiB (two d-planes)

    const size_t hbase = (size_t)b * T_TOT * DIM + (size_t)h * HEAD_DIM;

    // ---- stage K rows (linear quarters) ----
    for (int idx = tid; idx < ustage * 4; idx += 512) {
        const int u = idx >> 2, c = idx & 3;
        uint4 val = {0, 0, 0, 0};
        if (u < total) {
            const int g = (u < MEMN) ? u : klo + u - MEMN;
            val = *(const uint4*)(K + hbase + (size_t)g * DIM + c * 8);
        }
        *(uint4*)&sK[u][c * 8] = val;
    }
    // ---- stage V into two linear planes: plane p = d in [16p, 16p+16) ----
    for (int idx = tid; idx < ustage * 4; idx += 512) {
        const int pl   = (idx >= ustage * 2) ? 1 : 0;
        const int s    = idx - pl * ustage * 2;
        const int u    = s >> 1, half = s & 1;
        uint4 val = {0, 0, 0, 0};
        if (u < total) {
            const int g = (u < MEMN) ? u : klo + u - MEMN;
            val = *(const uint4*)(V + hbase + (size_t)g * DIM + pl * 16 + half * 8);
        }
        *(uint4*)&sV[pl][u][half * 8] = val;
    }

    // ---- Q fragment (pre-scaled): lane holds Q[q=fr][d=fq*8..+7] ----
    const int iq = i0 + wave * 16 + fr;
    const f16x8 qf = *(const f16x8*)(Q + (size_t)(b * T_TOT + iq) * DIM
                                     + h * HEAD_DIM + fq8);

    const int ulo  = max(iq - WHALF - klo, 0) + MEMN;
    const int uhi  = min(iq + WHALF, khi) - klo + MEMN;
    const int span = uhi - ulo;
    const int iw0  = i0 + wave * 16;
    const int ulo_minw = max(iw0 - WHALF - klo, 0) + MEMN;
    const int ulo_maxw = max(iw0 + 15 - WHALF - klo, 0) + MEMN;
    const int uhi_minw = min(iw0 + WHALF, khi) - klo + MEMN;
    const int uhi_maxw = min(iw0 + 15 + WHALF, khi) - klo + MEMN;
    const int glo = max(1, ulo_minw >> 5);
    const int ghi = uhi_maxw >> 5;

    // per-lane tr-read base (byte addr of sV plane0 + 8*lane)
    const uint vlane = (uint)(size_t)(&sV[0][0][0]) + (uint)(lane * 8);

    __syncthreads();

    const float NEGINF = -__builtin_huge_valf();
    float mns = 0.0f;
    float l   = 0.f;
    f32x4 oc0 = {0, 0, 0, 0}, oc1 = {0, 0, 0, 0};

    // ---------------- group 0: mem rows (unmasked) + rows 16-31 ----------------
    {
        const f16x8 kfA = *(const f16x8*)&sK[fr][fq8];
        const f16x8 kfB = *(const f16x8*)&sK[16 + fr][fq8];
        f32x4 sA = {0, 0, 0, 0}, sB = {0, 0, 0, 0};
        sA = __builtin_amdgcn_mfma_f32_16x16x32_f16(kfA, qf, sA, 0, 0, 0);
        sB = __builtin_amdgcn_mfma_f32_16x16x32_f16(kfB, qf, sB, 0, 0, 0);
        const uint vb = vlane;
        u32x2 t0 = tr64(vb), t1 = tr64(vb + 512);
        u32x2 t2 = tr64(vb + VPLANE), t3 = tr64(vb + VPLANE + 512);
        if (!(16 >= ulo_maxw && 31 <= uhi_minw)) {
            #pragma unroll
            for (int j = 0; j < 4; ++j) {
                const uint uu = (uint)(16 + fq4 + j - ulo);
                sB[j] = (uu <= (uint)span) ? sB[j] : NEGINF;
            }
        }
        float mx = fmaxf(fmaxf(fmaxf(sA[0], sA[1]), fmaxf(sA[2], sA[3])),
                         fmaxf(fmaxf(sB[0], sB[1]), fmaxf(sB[2], sB[3])));
        mx = fmaxf(mx, __shfl_xor(mx, 16));
        mx = fmaxf(mx, __shfl_xor(mx, 32));
        if (!__all(mx <= mns)) {
            const float mn2   = fmaxf(mns, mx);
            const float alpha = __expf(mns - mn2);
            l *= alpha;
            #pragma unroll
            for (int j = 0; j < 4; ++j) { oc0[j] *= alpha; oc1[j] *= alpha; }
            mns = mn2;
        }
        const float p0 = __expf(sA[0] - mns), p1 = __expf(sA[1] - mns);
        const float p2 = __expf(sA[2] - mns), p3 = __expf(sA[3] - mns);
        const float p4 = __expf(sB[0] - mns), p5 = __expf(sB[1] - mns);
        const float p6 = __expf(sB[2] - mns), p7 = __expf(sB[3] - mns);
        l += ((p0 + p1) + (p2 + p3)) + ((p4 + p5) + (p6 + p7));
        union { f16raw2 h2; uint u; } c0, c1, c2, c3;
        c0.h2 = __builtin_amdgcn_cvt_pkrtz(p0, p1);
        c1.h2 = __builtin_amdgcn_cvt_pkrtz(p2, p3);
        c2.h2 = __builtin_amdgcn_cvt_pkrtz(p4, p5);
        c3.h2 = __builtin_amdgcn_cvt_pkrtz(p6, p7);
        union { uint u[4]; f16x8 h; } P;
        P.u[0] = c0.u; P.u[1] = c1.u; P.u[2] = c2.u; P.u[3] = c3.u;
        asm volatile("s_waitcnt lgkmcnt(0)" ::: "memory");
        __builtin_amdgcn_sched_barrier(0);
        union { u32x2 d[2]; f16x8 h; } VA0, VA1;
        VA0.d[0] = t0; VA0.d[1] = t1;
        VA1.d[0] = t2; VA1.d[1] = t3;
        oc0 = __builtin_amdgcn_mfma_f32_16x16x32_f16(VA0.h, P.h, oc0, 0, 0, 0);
        oc1 = __builtin_amdgcn_mfma_f32_16x16x32_f16(VA1.h, P.h, oc1, 0, 0, 0);
    }

    // ---------------- window groups, two per iteration ----------------
    int g = glo;
    for (; g + 1 <= ghi; g += 2) {
        const int ua = g * 32, ub2 = ua + 32;
        const f16x8 kf0 = *(const f16x8*)&sK[ua + fr][fq8];
        const f16x8 kf1 = *(const f16x8*)&sK[ua + 16 + fr][fq8];
        const f16x8 kf2 = *(const f16x8*)&sK[ub2 + fr][fq8];
        const f16x8 kf3 = *(const f16x8*)&sK[ub2 + 16 + fr][fq8];
        f32x4 s0 = {0,0,0,0}, s1 = {0,0,0,0}, s2 = {0,0,0,0}, s3 = {0,0,0,0};
        s0 = __builtin_amdgcn_mfma_f32_16x16x32_f16(kf0, qf, s0, 0, 0, 0);
        s1 = __builtin_amdgcn_mfma_f32_16x16x32_f16(kf1, qf, s1, 0, 0, 0);
        s2 = __builtin_amdgcn_mfma_f32_16x16x32_f16(kf2, qf, s2, 0, 0, 0);
        s3 = __builtin_amdgcn_mfma_f32_16x16x32_f16(kf3, qf, s3, 0, 0, 0);
        const uint vb = vlane + (uint)(ua * 32);
        u32x2 ta0 = tr64(vb),          ta1 = tr64(vb + 512);
        u32x2 ta2 = tr64(vb + VPLANE), ta3 = tr64(vb + VPLANE + 512);
        u32x2 tb0 = tr64(vb + 1024),          tb1 = tr64(vb + 1536);
        u32x2 tb2 = tr64(vb + VPLANE + 1024), tb3 = tr64(vb + VPLANE + 1536);
        #pragma unroll
        for (int cch = 0; cch < 4; ++cch) {
            const int base = ua + cch * 16;
            f32x4& sc = cch == 0 ? s0 : (cch == 1 ? s1 : (cch == 2 ? s2 : s3));
            if (!(base >= ulo_maxw && base + 15 <= uhi_minw)) {
                #pragma unroll
                for (int j = 0; j < 4; ++j) {
                    const uint uu = (uint)(base + fq4 + j - ulo);
                    sc[j] = (uu <= (uint)span) ? sc[j] : NEGINF;
                }
            }
        }
        float mxA = fmaxf(fmaxf(fmaxf(s0[0], s0[1]), fmaxf(s0[2], s0[3])),
                          fmaxf(fmaxf(s1[0], s1[1]), fmaxf(s1[2], s1[3])));
        float mxB = fmaxf(fmaxf(fmaxf(s2[0], s2[1]), fmaxf(s2[2], s2[3])),
                          fmaxf(fmaxf(s3[0], s3[1]), fmaxf(s3[2], s3[3])));
        float mx = fmaxf(mxA, mxB);
        mx = fmaxf(mx, __shfl_xor(mx, 16));
        mx = fmaxf(mx, __shfl_xor(mx, 32));
        if (!__all(mx <= mns)) {
            const float mn2   = fmaxf(mns, mx);
            const float alpha = __expf(mns - mn2);
            l *= alpha;
            #pragma unroll
            for (int j = 0; j < 4; ++j) { oc0[j] *= alpha; oc1[j] *= alpha; }
            mns = mn2;
        }
        const float a0 = __expf(s0[0] - mns), a1 = __expf(s0[1] - mns);
        const float a2 = __expf(s0[2] - mns), a3 = __expf(s0[3] - mns);
        const float a4 = __expf(s1[0] - mns), a5 = __expf(s1[1] - mns);
        const float a6 = __expf(s1[2] - mns), a7 = __expf(s1[3] - mns);
        const float b0 = __expf(s2[0] - mns), b1 = __expf(s2[1] - mns);
        const float b2 = __expf(s2[2] - mns), b3 = __expf(s2[3] - mns);
        const float b4 = __expf(s3[0] - mns), b5 = __expf(s3[1] - mns);
        const float b6 = __expf(s3[2] - mns), b7 = __expf(s3[3] - mns);
        l += (((a0 + a1) + (a2 + a3)) + ((a4 + a5) + (a6 + a7)))
           + (((b0 + b1) + (b2 + b3)) + ((b4 + b5) + (b6 + b7)));
        union { f16raw2 h2; uint u; } d0, d1, d2, d3, e0, e1, e2, e3;
        d0.h2 = __builtin_amdgcn_cvt_pkrtz(a0, a1);
        d1.h2 = __builtin_amdgcn_cvt_pkrtz(a2, a3);
        d2.h2 = __builtin_amdgcn_cvt_pkrtz(a4, a5);
        d3.h2 = __builtin_amdgcn_cvt_pkrtz(a6, a7);
        e0.h2 = __builtin_amdgcn_cvt_pkrtz(b0, b1);
        e1.h2 = __builtin_amdgcn_cvt_pkrtz(b2, b3);
        e2.h2 = __builtin_amdgcn_cvt_pkrtz(b4, b5);
        e3.h2 = __builtin_amdgcn_cvt_pkrtz(b6, b7);
        union { uint u[4]; f16x8 h; } P0, P1;
        P0.u[0] = d0.u; P0.u[1] = d1.u; P0.u[2] = d2.u; P0.u[3] = d3.u;
        P1.u[0] = e0.u; P1.u[1] = e1.u; P1.u[2] = e2.u; P1.u[3] = e3.u;
        asm volatile("s_waitcnt lgkmcnt(0)" ::: "memory");
        __builtin_amdgcn_sched_barrier(0);
        union { u32x2 d[2]; f16x8 h; } A0, A1, B0, B1;
        A0.d[0] = ta0; A0.d[1] = ta1;
        A1.d[0] = ta2; A1.d[1] = ta3;
        B0.d[0] = tb0; B0.d[1] = tb1;
        B1.d[0] = tb2; B1.d[1] = tb3;
        oc0 = __builtin_amdgcn_mfma_f32_16x16x32_f16(A0.h, P0.h, oc0, 0, 0, 0);
        oc1 = __builtin_amdgcn_mfma_f32_16x16x32_f16(A1.h, P0.h, oc1, 0, 0, 0);
        oc0 = __builtin_amdgcn_mfma_f32_16x16x32_f16(B0.h, P1.h, oc0, 0, 0, 0);
        oc1 = __builtin_amdgcn_mfma_f32_16x16x32_f16(B1.h, P1.h, oc1, 0, 0, 0);
    }
    // odd tail group
    if (g <= ghi) {
        const int ua = g * 32;
        const f16x8 kf0 = *(const f16x8*)&sK[ua + fr][fq8];
        const f16x8 kf1 = *(const f16x8*)&sK[ua + 16 + fr][fq8];
        f32x4 s0 = {0,0,0,0}, s1 = {0,0,0,0};
        s0 = __builtin_amdgcn_mfma_f32_16x16x32_f16(kf0, qf, s0, 0, 0, 0);
        s1 = __builtin_amdgcn_mfma_f32_16x16x32_f16(kf1, qf, s1, 0, 0, 0);
        const uint vb = vlane + (uint)(ua * 32);
        u32x2 t0 = tr64(vb),          t1 = tr64(vb + 512);
        u32x2 t2 = tr64(vb + VPLANE), t3 = tr64(vb + VPLANE + 512);
        #pragma unroll
        for (int cch = 0; cch < 2; ++cch) {
            const int base = ua + cch * 16;
            f32x4& sc = cch == 0 ? s0 : s1;
            if (!(base >= ulo_maxw && base + 15 <= uhi_minw)) {
                #pragma unroll
                for (int j = 0; j < 4; ++j) {
                    const uint uu = (uint)(base + fq4 + j - ulo);
                    sc[j] = (uu <= (uint)span) ? sc[j] : NEGINF;
                }
            }
        }
        float mx = fmaxf(fmaxf(fmaxf(s0[0], s0[1]), fmaxf(s0[2], s0[3])),
                         fmaxf(fmaxf(s1[0], s1[1]), fmaxf(s1[2], s1[3])));
        mx = fmaxf(mx, __shfl_xor(mx, 16));
        mx = fmaxf(mx, __shfl_xor(mx, 32));
        if (!__all(mx <= mns)) {
            const float mn2   = fmaxf(mns, mx);
            const float alpha = __expf(mns - mn2);
            l *= alpha;
            #pragma unroll
            for (int j = 0; j < 4; ++j) { oc0[j] *= alpha; oc1[j] *= alpha; }
            mns = mn2;
        }
        const float p0 = __expf(s0[0] - mns), p1 = __expf(s0[1] - mns);
        const float p2 = __expf(s0[2] - mns), p3 = __expf(s0[3] - mns);
        const float p4 = __expf(s1[0] - mns), p5 = __expf(s1[1] - mns);
        const float p6 = __expf(s1[2] - mns), p7 = __expf(s1[3] - mns);
        l += ((p0 + p1) + (p2 + p3)) + ((p4 + p5) + (p6 + p7));
        union { f16raw2 h2; uint u; } c0, c1, c2, c3;
        c0.h2 = __builtin_amdgcn_cvt_pkrtz(p0, p1);
        c1.h2 = __builtin_amdgcn_cvt_pkrtz(p2, p3);
        c2.h2 = __builtin_amdgcn_cvt_pkrtz(p4, p5);
        c3.h2 = __builtin_amdgcn_cvt_pkrtz(p6, p7);
        union { uint u[4]; f16x8 h; } P;
        P.u[0] = c0.u; P.u[1] = c1.u; P.u[2] = c2.u; P.u[3] = c3.u;
        asm volatile("s_waitcnt lgkmcnt(0)" ::: "memory");
        __builtin_amdgcn_sched_barrier(0);
        union { u32x2 d[2]; f16x8 h; } VA0, VA1;
        VA0.d[0] = t0; VA0.d[1] = t1;
        VA1.d[0] = t2; VA1.d[1] = t3;
        oc0 = __builtin_amdgcn_mfma_f32_16x16x32_f16(VA0.h, P.h, oc0, 0, 0, 0);
        oc1 = __builtin_amdgcn_mfma_f32_16x16x32_f16(VA1.h, P.h, oc1, 0, 0, 0);
    }

    // ---- finalize ----
    l += __shfl_xor(l, 16);
    l += __shfl_xor(l, 32);
    const float inv = 1.0f / l;
    union { f16raw2 h2; uint u; } w00, w01, w10, w11;
    w00.h2 = __builtin_amdgcn_cvt_pkrtz(oc0[0] * inv, oc0[1] * inv);
    w01.h2 = __builtin_amdgcn_cvt_pkrtz(oc0[2] * inv, oc0[3] * inv);
    w10.h2 = __builtin_amdgcn_cvt_pkrtz(oc1[0] * inv, oc1[1] * inv);
    w11.h2 = __builtin_amdgcn_cvt_pkrtz(oc1[2] * inv, oc1[3] * inv);
    ushort* cp = ctx + ((size_t)b * SEQ + (iq - MEMN)) * DIM
               + h * HEAD_DIM + fq4;
    *(uint2*)cp        = (uint2){w00.u, w01.u};
    *(uint2*)(cp + 16) = (uint2){w10.u, w11.u};
}

// ---------------------------------------------------------------------------
extern "C" void kernel_launch(void* const* d_in, const int* in_sizes, int n_in,
                              void* d_out, int out_size, void* d_ws, size_t ws_size,
                              hipStream_t stream) {
    const float* q    = (const float*)d_in[0];
    const float* k    = (const float*)d_in[1];
    const float* v    = (const float*)d_in[2];
    const float* memp = (const float*)d_in[3];
    const float* Wq   = (const float*)d_in[4];
    const float* bq   = (const float*)d_in[5];
    const float* Wk   = (const float*)d_in[6];
    const float* bk   = (const float*)d_in[7];
    const float* Wv   = (const float*)d_in[8];
    const float* bv   = (const float*)d_in[9];
    const float* Wo   = (const float*)d_in[10];
    const float* bo   = (const float*)d_in[11];
    float* out = (float*)d_out;

    const size_t NX = (size_t)MROWS * DIM;
    const size_t NW = (size_t)DIM * DIM;
    const size_t NC = (size_t)OROWS * DIM;

    ushort* p   = (ushort*)d_ws;
    ushort* Xq  = p;            p += NX;
    ushort* Xk  = p;            p += NX;
    ushort* Xv  = p;            p += NX;
    ushort* Qc  = p;            p += NX;
    ushort* Kc  = p;            p += NX;
    ushort* Vc  = p;            p += NX;
    ushort* Wtq = p;            p += NW;
    ushort* Wtk = p;            p += NW;
    ushort* Wtv = p;            p += NW;
    ushort* Wto = p;            p += NW;
    ushort* Cc  = p;            p += NC;               // ~31.7 MB total

    dim3 gp((MROWS * DIM / 8 + 255) / 256, 1, 7);
    prep_cvt<<<gp, 256, 0, stream>>>(q, k, v, memp, Wq, Wk, Wv, Wo,
                                     Xq, Xk, Xv, Wtq, Wtk, Wtv, Wto);

    dim3 g1((MROWS + 63) / 64, 4, 3);                  // 65 x 4 x 3 = 780 blocks
    gemm_qkv<<<g1, 256, 0, stream>>>(Xq, Xk, Xv, Wtq, Wtk, Wtv,
                                     bq, bk, bv, Qc, Kc, Vc);

    dim3 g2(SEQ / QT, NUM_HEADS, BATCH);
    attn_mfma<<<g2, 512, 0, stream>>>(Qc, Kc, Vc, Cc);

    dim3 g3(OROWS / 64, 4, 1);                         // 64 x 4 = 256 blocks
    gemm_out64<<<g3, 256, 0, stream>>>(Cc, Wto, bo, out);
}